// Round 1
// 453.956 us; speedup vs baseline: 1.1268x; 1.1268x over previous
//
#include <hip/hip_runtime.h>
#include <stdint.h>

#define M_SIMP 100000
#define MPAD   100064
#define NNZV   800000
#define KTOT   6

typedef unsigned int u32;
typedef __attribute__((ext_vector_type(8))) short short8;
typedef __attribute__((ext_vector_type(4))) float f32x4;

__device__ __forceinline__ float bf2f(u32 u){ return __uint_as_float(u << 16); }
__device__ __forceinline__ u32 f2bf(float f){
    u32 u = __float_as_uint(f);
    return (u + 0x7FFFu + ((u >> 16) & 1u)) >> 16;   // RNE
}

// ---------------- pass 1: histogram + within-row rank (one atomic pass) ----
__global__ void k_histpe(const int* __restrict__ i0, int* __restrict__ c0, int* __restrict__ p0,
                         const int* __restrict__ i1, int* __restrict__ c1, int* __restrict__ p1){
    int e = blockIdx.x * 256 + threadIdx.x;
    const int* idx = blockIdx.y ? i1 : i0;
    int* cnt = blockIdx.y ? c1 : c0;
    int* pe  = blockIdx.y ? p1 : p0;
    if (e < NNZV){
        int r = idx[e];
        pe[e] = atomicAdd(&cnt[r], 1);
    }
}

// exclusive scan, 1024 elems/block
__global__ void k_scan1(const int* __restrict__ in0, int* __restrict__ out0, int* __restrict__ bs0,
                        const int* __restrict__ in1, int* __restrict__ out1, int* __restrict__ bs1,
                        int n){
    const int* in  = blockIdx.y ? in1 : in0;
    int* out   = blockIdx.y ? out1 : out0;
    int* bsums = blockIdx.y ? bs1 : bs0;
    __shared__ int s[256];
    int t = threadIdx.x;
    int base = blockIdx.x * 1024 + t * 4;
    int v0 = (base + 0 < n) ? in[base + 0] : 0;
    int v1 = (base + 1 < n) ? in[base + 1] : 0;
    int v2 = (base + 2 < n) ? in[base + 2] : 0;
    int v3 = (base + 3 < n) ? in[base + 3] : 0;
    int sum = v0 + v1 + v2 + v3;
    s[t] = sum;
    __syncthreads();
    for (int off = 1; off < 256; off <<= 1){
        int x = (t >= off) ? s[t - off] : 0;
        __syncthreads();
        s[t] += x;
        __syncthreads();
    }
    int excl = s[t] - sum;
    if (t == 255) bsums[blockIdx.x] = s[255];
    if (base + 0 < n) out[base + 0] = excl;
    if (base + 1 < n) out[base + 1] = excl + v0;
    if (base + 2 < n) out[base + 2] = excl + v0 + v1;
    if (base + 3 < n) out[base + 3] = excl + v0 + v1 + v2;
}

__global__ void k_scan2(int* __restrict__ b0, int* __restrict__ b1,
                        int* __restrict__ rp0, int* __restrict__ rp1, int nb){
    int t = threadIdx.x;
    if (t < 2){
        int* bs = t ? b1 : b0;
        int run = 0;
        for (int i = 0; i < nb; i++){ int x = bs[i]; bs[i] = run; run += x; }
    }
    if (t == 2) rp0[M_SIMP] = NNZV;
    if (t == 3) rp1[M_SIMP] = NNZV;
}

__global__ void k_scan3(int* __restrict__ o0, const int* __restrict__ b0,
                        int* __restrict__ o1, const int* __restrict__ b1, int n){
    int* out = blockIdx.y ? o1 : o0;
    const int* bsums = blockIdx.y ? b1 : b0;
    int base = blockIdx.x * 1024 + threadIdx.x * 4;
    int add = bsums[blockIdx.x];
    #pragma unroll
    for (int j = 0; j < 4; j++)
        if (base + j < n) out[base + j] += add;
}

// ---------------- pass 2: scatter packed (col,val) into CSR order ----------
// Replaces the pm permutation array: spmm then reads (col,val) SEQUENTIALLY,
// collapsing its dependent-load chain from 3 levels to 2.
__global__ void k_scatcv(const int* __restrict__ i0, const float* __restrict__ v0,
                         const int* __restrict__ pe0, const int* __restrict__ rp0,
                         uint2* __restrict__ cv0,
                         const int* __restrict__ i1, const float* __restrict__ v1,
                         const int* __restrict__ pe1, const int* __restrict__ rp1,
                         uint2* __restrict__ cv1){
    int e = blockIdx.x * 256 + threadIdx.x;
    const int* idx   = blockIdx.y ? i1 : i0;
    const float* val = blockIdx.y ? v1 : v0;
    const int* pe    = blockIdx.y ? pe1 : pe0;
    const int* rp    = blockIdx.y ? rp1 : rp0;
    uint2* cv        = blockIdx.y ? cv1 : cv0;
    if (e < NNZV){
        int r = idx[e];
        uint2 o;
        o.x = (u32)idx[NNZV + e];            // column
        o.y = __float_as_uint(val[e]);       // value bits
        cv[rp[r] + pe[e]] = o;
    }
}

// ---------------- transpose x (B,C,M) fp32 -> F0 (M,128) bf16 ----------------
__global__ void k_transpose(const float* __restrict__ x, u32* __restrict__ F0){
    __shared__ unsigned short s[64 * 130];
    int t = threadIdx.x;
    int m0 = blockIdx.x * 64;
    int j  = t & 63;
    int r4 = t >> 6;
    #pragma unroll 4
    for (int it = 0; it < 32; ++it){
        int bc = it * 4 + r4;
        int m  = m0 + j;
        if (m < M_SIMP)
            s[j * 130 + bc] = (unsigned short)f2bf(x[(size_t)bc * M_SIMP + m]);
    }
    __syncthreads();
    #pragma unroll 4
    for (int it = 0; it < 16; ++it){
        int m  = it * 4 + r4;
        int gm = m0 + m;
        if (gm < M_SIMP){
            u32 lo = s[m * 130 + 2 * j];
            u32 hi = s[m * 130 + 2 * j + 1];
            F0[(size_t)gm * 64 + j] = lo | (hi << 16);
        }
    }
}

// ---------------- SpMM: sequential (col,val) + uint4 gathers ----------------
// 16 rows/block; each row served by 16 lanes x uint4 (8 channels each).
// cv[j] is the same address across the 16 lanes of a row slot -> broadcast.
__global__ __launch_bounds__(256) void k_spmm(
    const int* __restrict__ rpA, const uint2* __restrict__ cvA,
    const u32* __restrict__ finA, u32* __restrict__ foutA,
    const int* __restrict__ rpB, const uint2* __restrict__ cvB,
    const u32* __restrict__ finB, u32* __restrict__ foutB)
{
    int t   = threadIdx.x;
    int sub = t >> 4;          // row slot 0..15
    int l   = t & 15;          // 8 channels per lane
    int row = blockIdx.x * 16 + sub;
    const int* rp; const uint2* cv; const u32* fin; u32* fout;
    if (blockIdx.y == 0){ rp=rpA; cv=cvA; fin=finA; fout=foutA; }
    else                { rp=rpB; cv=cvB; fin=finB; fout=foutB; }
    if (row >= M_SIMP) return;
    int s = rp[row], en = rp[row + 1];
    float a0=0,a1=0,a2=0,a3=0,a4=0,a5=0,a6=0,a7=0;
    int j = s;
    for (; j + 4 <= en; j += 4){
        uint2 q0 = cv[j], q1 = cv[j+1], q2 = cv[j+2], q3 = cv[j+3];
        uint4 g0 = *(const uint4*)(fin + (size_t)q0.x * 64 + l * 4);
        uint4 g1 = *(const uint4*)(fin + (size_t)q1.x * 64 + l * 4);
        uint4 g2 = *(const uint4*)(fin + (size_t)q2.x * 64 + l * 4);
        uint4 g3 = *(const uint4*)(fin + (size_t)q3.x * 64 + l * 4);
        float v0 = __uint_as_float(q0.y), v1 = __uint_as_float(q1.y);
        float v2 = __uint_as_float(q2.y), v3 = __uint_as_float(q3.y);
        a0 += v0*bf2f(g0.x&0xffffu) + v1*bf2f(g1.x&0xffffu) + v2*bf2f(g2.x&0xffffu) + v3*bf2f(g3.x&0xffffu);
        a1 += v0*bf2f(g0.x>>16)     + v1*bf2f(g1.x>>16)     + v2*bf2f(g2.x>>16)     + v3*bf2f(g3.x>>16);
        a2 += v0*bf2f(g0.y&0xffffu) + v1*bf2f(g1.y&0xffffu) + v2*bf2f(g2.y&0xffffu) + v3*bf2f(g3.y&0xffffu);
        a3 += v0*bf2f(g0.y>>16)     + v1*bf2f(g1.y>>16)     + v2*bf2f(g2.y>>16)     + v3*bf2f(g3.y>>16);
        a4 += v0*bf2f(g0.z&0xffffu) + v1*bf2f(g1.z&0xffffu) + v2*bf2f(g2.z&0xffffu) + v3*bf2f(g3.z&0xffffu);
        a5 += v0*bf2f(g0.z>>16)     + v1*bf2f(g1.z>>16)     + v2*bf2f(g2.z>>16)     + v3*bf2f(g3.z>>16);
        a6 += v0*bf2f(g0.w&0xffffu) + v1*bf2f(g1.w&0xffffu) + v2*bf2f(g2.w&0xffffu) + v3*bf2f(g3.w&0xffffu);
        a7 += v0*bf2f(g0.w>>16)     + v1*bf2f(g1.w>>16)     + v2*bf2f(g2.w>>16)     + v3*bf2f(g3.w>>16);
    }
    for (; j < en; j++){
        uint2 q = cv[j];
        float v = __uint_as_float(q.y);
        uint4 g = *(const uint4*)(fin + (size_t)q.x * 64 + l * 4);
        a0 += v*bf2f(g.x&0xffffu); a1 += v*bf2f(g.x>>16);
        a2 += v*bf2f(g.y&0xffffu); a3 += v*bf2f(g.y>>16);
        a4 += v*bf2f(g.z&0xffffu); a5 += v*bf2f(g.z>>16);
        a6 += v*bf2f(g.w&0xffffu); a7 += v*bf2f(g.w>>16);
    }
    uint4 o;
    o.x = f2bf(a0) | (f2bf(a1) << 16);
    o.y = f2bf(a2) | (f2bf(a3) << 16);
    o.z = f2bf(a4) | (f2bf(a5) << 16);
    o.w = f2bf(a6) | (f2bf(a7) << 16);
    *(uint4*)(fout + (size_t)row * 64 + l * 4) = o;
}

// ---------------- theta (o,i,k) fp32 -> Wb bf16 [k][o][i] packed u32 ----------------
__global__ void k_wb(const float* __restrict__ theta, u32* __restrict__ Wb){
    int idx = blockIdx.x * 256 + threadIdx.x;
    if (idx < KTOT * 64 * 32){
        int km = idx >> 11;
        int r  = idx & 2047;
        int o  = r >> 5;
        int i2 = (r & 31) * 2;
        u32 lo = f2bf(theta[o * 384 + i2 * 6 + km]);
        u32 hi = f2bf(theta[o * 384 + (i2 + 1) * 6 + km]);
        Wb[idx] = lo | (hi << 16);
    }
}

// ---------------- MFMA GEMM ----------------
__global__ __launch_bounds__(256) void k_gemm(
    const u32* __restrict__ F0, const u32* __restrict__ F1, const u32* __restrict__ F2,
    const u32* __restrict__ F4, const u32* __restrict__ F5,
    const u32* __restrict__ Wb, const float* __restrict__ bias, float* __restrict__ out)
{
    int t    = threadIdx.x;
    int wave = t >> 6;
    int lane = t & 63;
    int q    = lane >> 4;
    int l16  = lane & 15;
    int bm   = blockIdx.x * 64;
    int b    = blockIdx.y;
    const u32* __restrict__ Fs[6] = {F0, F1, F2, F0, F4, F5};

    f32x4 acc0 = {0.f,0.f,0.f,0.f}, acc1 = {0.f,0.f,0.f,0.f};
    f32x4 acc2 = {0.f,0.f,0.f,0.f}, acc3 = {0.f,0.f,0.f,0.f};

    int o_a = wave * 16 + l16;
    size_t mr0 = (size_t)(bm +  0 + l16) * 64 + b * 32;
    size_t mr1 = (size_t)(bm + 16 + l16) * 64 + b * 32;
    size_t mr2 = (size_t)(bm + 32 + l16) * 64 + b * 32;
    size_t mr3 = (size_t)(bm + 48 + l16) * 64 + b * 32;

    #pragma unroll
    for (int km = 0; km < KTOT; km++){
        const u32* __restrict__ F = Fs[km];
        const u32* __restrict__ W = Wb + (km * 64 + o_a) * 32;
        #pragma unroll
        for (int h = 0; h < 2; h++){
            int koff = h * 16 + q * 4;
            short8 a   = *(const short8*)(W + koff);
            short8 bb0 = *(const short8*)(F + mr0 + koff);
            short8 bb1 = *(const short8*)(F + mr1 + koff);
            short8 bb2 = *(const short8*)(F + mr2 + koff);
            short8 bb3 = *(const short8*)(F + mr3 + koff);
            acc0 = __builtin_amdgcn_mfma_f32_16x16x32_bf16(a, bb0, acc0, 0, 0, 0);
            acc1 = __builtin_amdgcn_mfma_f32_16x16x32_bf16(a, bb1, acc1, 0, 0, 0);
            acc2 = __builtin_amdgcn_mfma_f32_16x16x32_bf16(a, bb2, acc2, 0, 0, 0);
            acc3 = __builtin_amdgcn_mfma_f32_16x16x32_bf16(a, bb3, acc3, 0, 0, 0);
        }
    }

    int ob = wave * 16 + q * 4;
    float bv0 = bias[ob], bv1 = bias[ob+1], bv2 = bias[ob+2], bv3 = bias[ob+3];
    f32x4 accs[4] = {acc0, acc1, acc2, acc3};
    #pragma unroll
    for (int ms = 0; ms < 4; ms++){
        int gm = bm + ms * 16 + l16;
        if (gm < M_SIMP){
            size_t base = (size_t)(b * 64 + ob) * M_SIMP + gm;
            out[base             ] = accs[ms][0] + bv0;
            out[base + 1ul*M_SIMP] = accs[ms][1] + bv1;
            out[base + 2ul*M_SIMP] = accs[ms][2] + bv2;
            out[base + 3ul*M_SIMP] = accs[ms][3] + bv3;
        }
    }
}

extern "C" void kernel_launch(void* const* d_in, const int* in_sizes, int n_in,
                              void* d_out, int out_size, void* d_ws, size_t ws_size,
                              hipStream_t stream)
{
    const int*   Ll_idx = (const int*)d_in[0];
    const float* Ll_val = (const float*)d_in[1];
    const int*   Lu_idx = (const int*)d_in[2];
    const float* Lu_val = (const float*)d_in[3];
    const float* x      = (const float*)d_in[4];
    const float* theta  = (const float*)d_in[5];
    const float* bias   = (const float*)d_in[6];
    float* out = (float*)d_out;

    char* ws = (char*)d_ws;
    size_t off = 0;
    auto take = [&](size_t bytes) -> char* {
        char* p = ws + off;
        off = (off + bytes + 255) & ~(size_t)255;
        return p;
    };
    const size_t FB = (size_t)MPAD * 64 * 4;
    u32* F0 = (u32*)take(FB);
    u32* F1 = (u32*)take(FB);
    u32* F2 = (u32*)take(FB);
    u32* F4 = (u32*)take(FB);
    u32* F5 = (u32*)take(FB);
    u32* Wb = (u32*)take((size_t)KTOT * 64 * 32 * 4);
    int* cnt_l = (int*)take((size_t)M_SIMP * 4);
    int* cnt_u = (int*)take((size_t)M_SIMP * 4);
    int* rp_l  = (int*)take((size_t)(M_SIMP + 1) * 4);
    int* rp_u  = (int*)take((size_t)(M_SIMP + 1) * 4);
    int* pe_l  = (int*)take((size_t)NNZV * 4);
    int* pe_u  = (int*)take((size_t)NNZV * 4);
    uint2* cv_l = (uint2*)take((size_t)NNZV * 8);
    uint2* cv_u = (uint2*)take((size_t)NNZV * 8);
    int* bs_l = (int*)take(512);
    int* bs_u = (int*)take(512);

    hipMemsetAsync(cnt_l, 0, (size_t)M_SIMP * 4, stream);
    hipMemsetAsync(cnt_u, 0, (size_t)M_SIMP * 4, stream);

    const int NBH = (NNZV + 255) / 256;       // 3125
    dim3 gh(NBH, 2);
    k_histpe<<<gh, 256, 0, stream>>>(Ll_idx, cnt_l, pe_l, Lu_idx, cnt_u, pe_u);

    const int NBS = (M_SIMP + 1023) / 1024;   // 98
    dim3 gs(NBS, 2);
    k_scan1<<<gs, 256, 0, stream>>>(cnt_l, rp_l, bs_l, cnt_u, rp_u, bs_u, M_SIMP);
    k_scan2<<<1, 64, 0, stream>>>(bs_l, bs_u, rp_l, rp_u, NBS);
    k_scan3<<<gs, 256, 0, stream>>>(rp_l, bs_l, rp_u, bs_u, M_SIMP);

    k_scatcv<<<gh, 256, 0, stream>>>(Ll_idx, Ll_val, pe_l, rp_l, cv_l,
                                     Lu_idx, Lu_val, pe_u, rp_u, cv_u);

    const int NBT = (M_SIMP + 63) / 64;       // 1563
    k_transpose<<<NBT, 256, 0, stream>>>(x, F0);
    k_wb<<<(KTOT * 64 * 32 + 255) / 256, 256, 0, stream>>>(theta, Wb);

    const int NBM = (M_SIMP + 15) / 16;       // 6250
    dim3 gm(NBM, 2);
    k_spmm<<<gm, 256, 0, stream>>>(rp_l, cv_l, F0, F1,
                                   rp_u, cv_u, F0, F4);
    k_spmm<<<gm, 256, 0, stream>>>(rp_l, cv_l, F1, F2,
                                   rp_u, cv_u, F4, F5);

    dim3 gg(NBT, 2);
    k_gemm<<<gg, 256, 0, stream>>>(F0, F1, F2, F4, F5, Wb, bias, out);
}

// Round 3
// 452.462 us; speedup vs baseline: 1.1305x; 1.0033x over previous
//
#include <hip/hip_runtime.h>
#include <stdint.h>

#define M_SIMP 100000
#define MPAD   100064
#define NNZV   800000
#define KM5    5

typedef unsigned int u32;
typedef __attribute__((ext_vector_type(8))) short short8;
typedef __attribute__((ext_vector_type(4))) float f32x4;

__device__ __forceinline__ float bf2f(u32 u){ return __uint_as_float(u << 16); }
__device__ __forceinline__ u32 f2bf(float f){
    u32 u = __float_as_uint(f);
    return (u + 0x7FFFu + ((u >> 16) & 1u)) >> 16;   // RNE
}

// ---------------- pass 1: histogram + within-row rank (one atomic pass) ----
__global__ void k_histpe(const int* __restrict__ i0, int* __restrict__ c0, int* __restrict__ p0,
                         const int* __restrict__ i1, int* __restrict__ c1, int* __restrict__ p1){
    int e = blockIdx.x * 256 + threadIdx.x;
    const int* idx = blockIdx.y ? i1 : i0;
    int* cnt = blockIdx.y ? c1 : c0;
    int* pe  = blockIdx.y ? p1 : p0;
    if (e < NNZV){
        int r = idx[e];
        pe[e] = atomicAdd(&cnt[r], 1);
    }
}

// exclusive scan, 1024 elems/block
__global__ void k_scan1(const int* __restrict__ in0, int* __restrict__ out0, int* __restrict__ bs0,
                        const int* __restrict__ in1, int* __restrict__ out1, int* __restrict__ bs1,
                        int n){
    const int* in  = blockIdx.y ? in1 : in0;
    int* out   = blockIdx.y ? out1 : out0;
    int* bsums = blockIdx.y ? bs1 : bs0;
    __shared__ int s[256];
    int t = threadIdx.x;
    int base = blockIdx.x * 1024 + t * 4;
    int v0 = (base + 0 < n) ? in[base + 0] : 0;
    int v1 = (base + 1 < n) ? in[base + 1] : 0;
    int v2 = (base + 2 < n) ? in[base + 2] : 0;
    int v3 = (base + 3 < n) ? in[base + 3] : 0;
    int sum = v0 + v1 + v2 + v3;
    s[t] = sum;
    __syncthreads();
    for (int off = 1; off < 256; off <<= 1){
        int x = (t >= off) ? s[t - off] : 0;
        __syncthreads();
        s[t] += x;
        __syncthreads();
    }
    int excl = s[t] - sum;
    if (t == 255) bsums[blockIdx.x] = s[255];
    if (base + 0 < n) out[base + 0] = excl;
    if (base + 1 < n) out[base + 1] = excl + v0;
    if (base + 2 < n) out[base + 2] = excl + v0 + v1;
    if (base + 3 < n) out[base + 3] = excl + v0 + v1 + v2;
}

__global__ void k_scan2(int* __restrict__ b0, int* __restrict__ b1,
                        int* __restrict__ rp0, int* __restrict__ rp1, int nb){
    int t = threadIdx.x;
    if (t < 2){
        int* bs = t ? b1 : b0;
        int run = 0;
        for (int i = 0; i < nb; i++){ int x = bs[i]; bs[i] = run; run += x; }
    }
    if (t == 2) rp0[M_SIMP] = NNZV;
    if (t == 3) rp1[M_SIMP] = NNZV;
}

__global__ void k_scan3(int* __restrict__ o0, const int* __restrict__ b0,
                        int* __restrict__ o1, const int* __restrict__ b1, int n){
    int* out = blockIdx.y ? o1 : o0;
    const int* bsums = blockIdx.y ? b1 : b0;
    int base = blockIdx.x * 1024 + threadIdx.x * 4;
    int add = bsums[blockIdx.x];
    #pragma unroll
    for (int j = 0; j < 4; j++)
        if (base + j < n) out[base + j] += add;
}

// ---------------- pass 2: scatter packed (col,val) into CSR order ----------
__global__ void k_scatcv(const int* __restrict__ i0, const float* __restrict__ v0,
                         const int* __restrict__ pe0, const int* __restrict__ rp0,
                         uint2* __restrict__ cv0,
                         const int* __restrict__ i1, const float* __restrict__ v1,
                         const int* __restrict__ pe1, const int* __restrict__ rp1,
                         uint2* __restrict__ cv1){
    int e = blockIdx.x * 256 + threadIdx.x;
    const int* idx   = blockIdx.y ? i1 : i0;
    const float* val = blockIdx.y ? v1 : v0;
    const int* pe    = blockIdx.y ? pe1 : pe0;
    const int* rp    = blockIdx.y ? rp1 : rp0;
    uint2* cv        = blockIdx.y ? cv1 : cv0;
    if (e < NNZV){
        int r = idx[e];
        uint2 o;
        o.x = (u32)idx[NNZV + e];            // column
        o.y = __float_as_uint(val[e]);       // value bits
        cv[rp[r] + pe[e]] = o;
    }
}

// ---------------- transpose x (B,C,M) fp32 -> F0 (M,128) bf16 ----------------
__global__ void k_transpose(const float* __restrict__ x, u32* __restrict__ F0){
    __shared__ unsigned short s[64 * 130];
    int t = threadIdx.x;
    int m0 = blockIdx.x * 64;
    int j  = t & 63;
    int r4 = t >> 6;
    #pragma unroll 4
    for (int it = 0; it < 32; ++it){
        int bc = it * 4 + r4;
        int m  = m0 + j;
        if (m < M_SIMP)
            s[j * 130 + bc] = (unsigned short)f2bf(x[(size_t)bc * M_SIMP + m]);
    }
    __syncthreads();
    #pragma unroll 4
    for (int it = 0; it < 16; ++it){
        int m  = it * 4 + r4;
        int gm = m0 + m;
        if (gm < M_SIMP){
            u32 lo = s[m * 130 + 2 * j];
            u32 hi = s[m * 130 + 2 * j + 1];
            F0[(size_t)gm * 64 + j] = lo | (hi << 16);
        }
    }
}

// ---------------- SpMM: sequential (col,val) + uint4 gathers ----------------
__global__ __launch_bounds__(256) void k_spmm(
    const int* __restrict__ rpA, const uint2* __restrict__ cvA,
    const u32* __restrict__ finA, u32* __restrict__ foutA,
    const int* __restrict__ rpB, const uint2* __restrict__ cvB,
    const u32* __restrict__ finB, u32* __restrict__ foutB)
{
    int t   = threadIdx.x;
    int sub = t >> 4;          // row slot 0..15
    int l   = t & 15;          // 8 channels per lane
    int row = blockIdx.x * 16 + sub;
    const int* rp; const uint2* cv; const u32* fin; u32* fout;
    if (blockIdx.y == 0){ rp=rpA; cv=cvA; fin=finA; fout=foutA; }
    else                { rp=rpB; cv=cvB; fin=finB; fout=foutB; }
    if (row >= M_SIMP) return;
    int s = rp[row], en = rp[row + 1];
    float a0=0,a1=0,a2=0,a3=0,a4=0,a5=0,a6=0,a7=0;
    int j = s;
    for (; j + 4 <= en; j += 4){
        uint2 q0 = cv[j], q1 = cv[j+1], q2 = cv[j+2], q3 = cv[j+3];
        uint4 g0 = *(const uint4*)(fin + (size_t)q0.x * 64 + l * 4);
        uint4 g1 = *(const uint4*)(fin + (size_t)q1.x * 64 + l * 4);
        uint4 g2 = *(const uint4*)(fin + (size_t)q2.x * 64 + l * 4);
        uint4 g3 = *(const uint4*)(fin + (size_t)q3.x * 64 + l * 4);
        float v0 = __uint_as_float(q0.y), v1 = __uint_as_float(q1.y);
        float v2 = __uint_as_float(q2.y), v3 = __uint_as_float(q3.y);
        a0 += v0*bf2f(g0.x&0xffffu) + v1*bf2f(g1.x&0xffffu) + v2*bf2f(g2.x&0xffffu) + v3*bf2f(g3.x&0xffffu);
        a1 += v0*bf2f(g0.x>>16)     + v1*bf2f(g1.x>>16)     + v2*bf2f(g2.x>>16)     + v3*bf2f(g3.x>>16);
        a2 += v0*bf2f(g0.y&0xffffu) + v1*bf2f(g1.y&0xffffu) + v2*bf2f(g2.y&0xffffu) + v3*bf2f(g3.y&0xffffu);
        a3 += v0*bf2f(g0.y>>16)     + v1*bf2f(g1.y>>16)     + v2*bf2f(g2.y>>16)     + v3*bf2f(g3.y>>16);
        a4 += v0*bf2f(g0.z&0xffffu) + v1*bf2f(g1.z&0xffffu) + v2*bf2f(g2.z&0xffffu) + v3*bf2f(g3.z&0xffffu);
        a5 += v0*bf2f(g0.z>>16)     + v1*bf2f(g1.z>>16)     + v2*bf2f(g2.z>>16)     + v3*bf2f(g3.z>>16);
        a6 += v0*bf2f(g0.w&0xffffu) + v1*bf2f(g1.w&0xffffu) + v2*bf2f(g2.w&0xffffu) + v3*bf2f(g3.w&0xffffu);
        a7 += v0*bf2f(g0.w>>16)     + v1*bf2f(g1.w>>16)     + v2*bf2f(g2.w>>16)     + v3*bf2f(g3.w>>16);
    }
    for (; j < en; j++){
        uint2 q = cv[j];
        float v = __uint_as_float(q.y);
        uint4 g = *(const uint4*)(fin + (size_t)q.x * 64 + l * 4);
        a0 += v*bf2f(g.x&0xffffu); a1 += v*bf2f(g.x>>16);
        a2 += v*bf2f(g.y&0xffffu); a3 += v*bf2f(g.y>>16);
        a4 += v*bf2f(g.z&0xffffu); a5 += v*bf2f(g.z>>16);
        a6 += v*bf2f(g.w&0xffffu); a7 += v*bf2f(g.w>>16);
    }
    uint4 o;
    o.x = f2bf(a0) | (f2bf(a1) << 16);
    o.y = f2bf(a2) | (f2bf(a3) << 16);
    o.z = f2bf(a4) | (f2bf(a5) << 16);
    o.w = f2bf(a6) | (f2bf(a7) << 16);
    *(uint4*)(fout + (size_t)row * 64 + l * 4) = o;
}

// ---------------- theta (o,i,k) fp32 -> Wb bf16 [km][o][i] packed u32 -------
// km slots: 0 -> theta_k0 + theta_k3 (both multiply F0), 1->k1, 2->k2, 3->k4, 4->k5
__global__ void k_wb(const float* __restrict__ theta, u32* __restrict__ Wb){
    int idx = blockIdx.x * 256 + threadIdx.x;
    if (idx < KM5 * 64 * 32){
        int km = idx >> 11;
        int r  = idx & 2047;
        int o  = r >> 5;
        int i2 = (r & 31) * 2;
        int k  = (km == 0) ? 0 : ((km < 3) ? km : km + 1);   // 0,1,2,4,5
        float lo = theta[o * 384 + i2 * 6 + k];
        float hi = theta[o * 384 + (i2 + 1) * 6 + k];
        if (km == 0){
            lo += theta[o * 384 + i2 * 6 + 3];
            hi += theta[o * 384 + (i2 + 1) * 6 + 3];
        }
        Wb[idx] = f2bf(lo) | (f2bf(hi) << 16);
    }
}

// ---------------- MFMA GEMM: both batches fused, 5 K-steps ------------------
// Block: 64 m-rows x 64 o x both b. Wave: 16 o, 4 m-subtiles, 2 b -> 8 acc.
// Each 256B F row is consumed entirely by one block (no cross-XCD dup fetch).
__global__ __launch_bounds__(256) void k_gemm(
    const u32* __restrict__ F0, const u32* __restrict__ F1, const u32* __restrict__ F2,
    const u32* __restrict__ F4, const u32* __restrict__ F5,
    const u32* __restrict__ Wb, const float* __restrict__ bias, float* __restrict__ out)
{
    int t    = threadIdx.x;
    int wave = t >> 6;
    int lane = t & 63;
    int q    = lane >> 4;
    int l16  = lane & 15;
    int bm   = blockIdx.x * 64;
    const u32* __restrict__ Fs[KM5] = {F0, F1, F2, F4, F5};

    f32x4 a00 = {0.f,0.f,0.f,0.f}, a10 = {0.f,0.f,0.f,0.f};
    f32x4 a20 = {0.f,0.f,0.f,0.f}, a30 = {0.f,0.f,0.f,0.f};
    f32x4 a01 = {0.f,0.f,0.f,0.f}, a11 = {0.f,0.f,0.f,0.f};
    f32x4 a21 = {0.f,0.f,0.f,0.f}, a31 = {0.f,0.f,0.f,0.f};

    int o_a = wave * 16 + l16;
    size_t r0 = (size_t)(bm +  0 + l16) * 64;
    size_t r1 = (size_t)(bm + 16 + l16) * 64;
    size_t r2 = (size_t)(bm + 32 + l16) * 64;
    size_t r3 = (size_t)(bm + 48 + l16) * 64;

    #pragma unroll
    for (int km = 0; km < KM5; km++){
        const u32* __restrict__ F = Fs[km];
        const u32* __restrict__ W = Wb + (km * 64 + o_a) * 32;
        #pragma unroll
        for (int h = 0; h < 2; h++){
            int koff = h * 16 + q * 4;
            short8 a    = *(const short8*)(W + koff);
            short8 b00  = *(const short8*)(F + r0 + koff);
            short8 b10  = *(const short8*)(F + r1 + koff);
            short8 b20  = *(const short8*)(F + r2 + koff);
            short8 b30  = *(const short8*)(F + r3 + koff);
            short8 b01  = *(const short8*)(F + r0 + 32 + koff);
            short8 b11  = *(const short8*)(F + r1 + 32 + koff);
            short8 b21  = *(const short8*)(F + r2 + 32 + koff);
            short8 b31  = *(const short8*)(F + r3 + 32 + koff);
            a00 = __builtin_amdgcn_mfma_f32_16x16x32_bf16(a, b00, a00, 0, 0, 0);
            a10 = __builtin_amdgcn_mfma_f32_16x16x32_bf16(a, b10, a10, 0, 0, 0);
            a20 = __builtin_amdgcn_mfma_f32_16x16x32_bf16(a, b20, a20, 0, 0, 0);
            a30 = __builtin_amdgcn_mfma_f32_16x16x32_bf16(a, b30, a30, 0, 0, 0);
            a01 = __builtin_amdgcn_mfma_f32_16x16x32_bf16(a, b01, a01, 0, 0, 0);
            a11 = __builtin_amdgcn_mfma_f32_16x16x32_bf16(a, b11, a11, 0, 0, 0);
            a21 = __builtin_amdgcn_mfma_f32_16x16x32_bf16(a, b21, a21, 0, 0, 0);
            a31 = __builtin_amdgcn_mfma_f32_16x16x32_bf16(a, b31, a31, 0, 0, 0);
        }
    }

    int ob = wave * 16 + q * 4;
    float bv0 = bias[ob], bv1 = bias[ob+1], bv2 = bias[ob+2], bv3 = bias[ob+3];
    f32x4 accs0[4] = {a00, a10, a20, a30};
    f32x4 accs1[4] = {a01, a11, a21, a31};
    #pragma unroll
    for (int ms = 0; ms < 4; ms++){
        int gm = bm + ms * 16 + l16;
        if (gm < M_SIMP){
            size_t base0 = (size_t)(0 * 64 + ob) * M_SIMP + gm;
            size_t base1 = (size_t)(1 * 64 + ob) * M_SIMP + gm;
            out[base0             ] = accs0[ms][0] + bv0;
            out[base0 + 1ul*M_SIMP] = accs0[ms][1] + bv1;
            out[base0 + 2ul*M_SIMP] = accs0[ms][2] + bv2;
            out[base0 + 3ul*M_SIMP] = accs0[ms][3] + bv3;
            out[base1             ] = accs1[ms][0] + bv0;
            out[base1 + 1ul*M_SIMP] = accs1[ms][1] + bv1;
            out[base1 + 2ul*M_SIMP] = accs1[ms][2] + bv2;
            out[base1 + 3ul*M_SIMP] = accs1[ms][3] + bv3;
        }
    }
}

extern "C" void kernel_launch(void* const* d_in, const int* in_sizes, int n_in,
                              void* d_out, int out_size, void* d_ws, size_t ws_size,
                              hipStream_t stream)
{
    const int*   Ll_idx = (const int*)d_in[0];
    const float* Ll_val = (const float*)d_in[1];
    const int*   Lu_idx = (const int*)d_in[2];
    const float* Lu_val = (const float*)d_in[3];
    const float* x      = (const float*)d_in[4];
    const float* theta  = (const float*)d_in[5];
    const float* bias   = (const float*)d_in[6];
    float* out = (float*)d_out;

    char* ws = (char*)d_ws;
    size_t off = 0;
    auto take = [&](size_t bytes) -> char* {
        char* p = ws + off;
        off = (off + bytes + 255) & ~(size_t)255;
        return p;
    };
    const size_t FB = (size_t)MPAD * 64 * 4;
    u32* F0 = (u32*)take(FB);
    u32* F1 = (u32*)take(FB);
    u32* F2 = (u32*)take(FB);
    u32* F4 = (u32*)take(FB);
    u32* F5 = (u32*)take(FB);
    u32* Wb = (u32*)take((size_t)KM5 * 64 * 32 * 4);
    int* cnt_l = (int*)take((size_t)M_SIMP * 4);
    int* cnt_u = (int*)take((size_t)M_SIMP * 4);
    int* rp_l  = (int*)take((size_t)(M_SIMP + 1) * 4);
    int* rp_u  = (int*)take((size_t)(M_SIMP + 1) * 4);
    int* pe_l  = (int*)take((size_t)NNZV * 4);
    int* pe_u  = (int*)take((size_t)NNZV * 4);
    uint2* cv_l = (uint2*)take((size_t)NNZV * 8);
    uint2* cv_u = (uint2*)take((size_t)NNZV * 8);
    int* bs_l = (int*)take(512);
    int* bs_u = (int*)take(512);

    hipMemsetAsync(cnt_l, 0, (size_t)M_SIMP * 4, stream);
    hipMemsetAsync(cnt_u, 0, (size_t)M_SIMP * 4, stream);

    const int NBH = (NNZV + 255) / 256;       // 3125
    dim3 gh(NBH, 2);
    k_histpe<<<gh, 256, 0, stream>>>(Ll_idx, cnt_l, pe_l, Lu_idx, cnt_u, pe_u);

    const int NBS = (M_SIMP + 1023) / 1024;   // 98
    dim3 gs(NBS, 2);
    k_scan1<<<gs, 256, 0, stream>>>(cnt_l, rp_l, bs_l, cnt_u, rp_u, bs_u, M_SIMP);
    k_scan2<<<1, 64, 0, stream>>>(bs_l, bs_u, rp_l, rp_u, NBS);
    k_scan3<<<gs, 256, 0, stream>>>(rp_l, bs_l, rp_u, bs_u, M_SIMP);

    k_scatcv<<<gh, 256, 0, stream>>>(Ll_idx, Ll_val, pe_l, rp_l, cv_l,
                                     Lu_idx, Lu_val, pe_u, rp_u, cv_u);

    const int NBT = (M_SIMP + 63) / 64;       // 1563
    k_transpose<<<NBT, 256, 0, stream>>>(x, F0);
    k_wb<<<(KM5 * 64 * 32 + 255) / 256, 256, 0, stream>>>(theta, Wb);

    const int NBM = (M_SIMP + 15) / 16;       // 6250
    dim3 gm(NBM, 2);
    k_spmm<<<gm, 256, 0, stream>>>(rp_l, cv_l, F0, F1,
                                   rp_u, cv_u, F0, F4);
    k_spmm<<<gm, 256, 0, stream>>>(rp_l, cv_l, F1, F2,
                                   rp_u, cv_u, F4, F5);

    k_gemm<<<NBT, 256, 0, stream>>>(F0, F1, F2, F4, F5, Wb, bias, out);
}

// Round 4
// 411.165 us; speedup vs baseline: 1.2441x; 1.1004x over previous
//
#include <hip/hip_runtime.h>
#include <stdint.h>

#define M_SIMP 100000
#define MPAD   100064
#define NNZV   800000
#define KM5    5

typedef unsigned int u32;
typedef __attribute__((ext_vector_type(8))) short short8;
typedef __attribute__((ext_vector_type(4))) float f32x4;

__device__ __forceinline__ float bf2f(u32 u){ return __uint_as_float(u << 16); }
__device__ __forceinline__ u32 f2bf(float f){
    u32 u = __float_as_uint(f);
    return (u + 0x7FFFu + ((u >> 16) & 1u)) >> 16;   // RNE
}

// ---------------- pass 1: histogram + within-row rank (one atomic pass) ----
__global__ void k_histpe(const int* __restrict__ i0, int* __restrict__ c0, int* __restrict__ p0,
                         const int* __restrict__ i1, int* __restrict__ c1, int* __restrict__ p1){
    int e = blockIdx.x * 256 + threadIdx.x;
    const int* idx = blockIdx.y ? i1 : i0;
    int* cnt = blockIdx.y ? c1 : c0;
    int* pe  = blockIdx.y ? p1 : p0;
    if (e < NNZV){
        int r = idx[e];
        pe[e] = atomicAdd(&cnt[r], 1);
    }
}

// exclusive scan, 1024 elems/block
__global__ void k_scan1(const int* __restrict__ in0, int* __restrict__ out0, int* __restrict__ bs0,
                        const int* __restrict__ in1, int* __restrict__ out1, int* __restrict__ bs1,
                        int n){
    const int* in  = blockIdx.y ? in1 : in0;
    int* out   = blockIdx.y ? out1 : out0;
    int* bsums = blockIdx.y ? bs1 : bs0;
    __shared__ int s[256];
    int t = threadIdx.x;
    int base = blockIdx.x * 1024 + t * 4;
    int v0 = (base + 0 < n) ? in[base + 0] : 0;
    int v1 = (base + 1 < n) ? in[base + 1] : 0;
    int v2 = (base + 2 < n) ? in[base + 2] : 0;
    int v3 = (base + 3 < n) ? in[base + 3] : 0;
    int sum = v0 + v1 + v2 + v3;
    s[t] = sum;
    __syncthreads();
    for (int off = 1; off < 256; off <<= 1){
        int x = (t >= off) ? s[t - off] : 0;
        __syncthreads();
        s[t] += x;
        __syncthreads();
    }
    int excl = s[t] - sum;
    if (t == 255) bsums[blockIdx.x] = s[255];
    if (base + 0 < n) out[base + 0] = excl;
    if (base + 1 < n) out[base + 1] = excl + v0;
    if (base + 2 < n) out[base + 2] = excl + v0 + v1;
    if (base + 3 < n) out[base + 3] = excl + v0 + v1 + v2;
}

__global__ void k_scan2(int* __restrict__ b0, int* __restrict__ b1,
                        int* __restrict__ rp0, int* __restrict__ rp1, int nb){
    int t = threadIdx.x;
    if (t < 2){
        int* bs = t ? b1 : b0;
        int run = 0;
        for (int i = 0; i < nb; i++){ int x = bs[i]; bs[i] = run; run += x; }
    }
    if (t == 2) rp0[M_SIMP] = NNZV;
    if (t == 3) rp1[M_SIMP] = NNZV;
}

__global__ void k_scan3(int* __restrict__ o0, const int* __restrict__ b0,
                        int* __restrict__ o1, const int* __restrict__ b1, int n){
    int* out = blockIdx.y ? o1 : o0;
    const int* bsums = blockIdx.y ? b1 : b0;
    int base = blockIdx.x * 1024 + threadIdx.x * 4;
    int add = bsums[blockIdx.x];
    #pragma unroll
    for (int j = 0; j < 4; j++)
        if (base + j < n) out[base + j] += add;
}

// ---------------- pass 2: scatter packed (col,val) into CSR order ----------
__global__ void k_scatcv(const int* __restrict__ i0, const float* __restrict__ v0,
                         const int* __restrict__ pe0, const int* __restrict__ rp0,
                         uint2* __restrict__ cv0,
                         const int* __restrict__ i1, const float* __restrict__ v1,
                         const int* __restrict__ pe1, const int* __restrict__ rp1,
                         uint2* __restrict__ cv1){
    int e = blockIdx.x * 256 + threadIdx.x;
    const int* idx   = blockIdx.y ? i1 : i0;
    const float* val = blockIdx.y ? v1 : v0;
    const int* pe    = blockIdx.y ? pe1 : pe0;
    const int* rp    = blockIdx.y ? rp1 : rp0;
    uint2* cv        = blockIdx.y ? cv1 : cv0;
    if (e < NNZV){
        int r = idx[e];
        uint2 o;
        o.x = (u32)idx[NNZV + e];            // column
        o.y = __float_as_uint(val[e]);       // value bits
        cv[rp[r] + pe[e]] = o;
    }
}

// ---------------- transpose x (B,C,M) fp32 -> F0 (M,128) bf16 ----------------
__global__ void k_transpose(const float* __restrict__ x, u32* __restrict__ F0){
    __shared__ unsigned short s[64 * 130];
    int t = threadIdx.x;
    int m0 = blockIdx.x * 64;
    int j  = t & 63;
    int r4 = t >> 6;
    #pragma unroll 4
    for (int it = 0; it < 32; ++it){
        int bc = it * 4 + r4;
        int m  = m0 + j;
        if (m < M_SIMP)
            s[j * 130 + bc] = (unsigned short)f2bf(x[(size_t)bc * M_SIMP + m]);
    }
    __syncthreads();
    #pragma unroll 4
    for (int it = 0; it < 16; ++it){
        int m  = it * 4 + r4;
        int gm = m0 + m;
        if (gm < M_SIMP){
            u32 lo = s[m * 130 + 2 * j];
            u32 hi = s[m * 130 + 2 * j + 1];
            F0[(size_t)gm * 64 + j] = lo | (hi << 16);
        }
    }
}

// ---------------- SpMM: sequential (col,val) + uint4 gathers ----------------
__global__ __launch_bounds__(256) void k_spmm(
    const int* __restrict__ rpA, const uint2* __restrict__ cvA,
    const u32* __restrict__ finA, u32* __restrict__ foutA,
    const int* __restrict__ rpB, const uint2* __restrict__ cvB,
    const u32* __restrict__ finB, u32* __restrict__ foutB)
{
    int t   = threadIdx.x;
    int sub = t >> 4;          // row slot 0..15
    int l   = t & 15;          // 8 channels per lane
    int row = blockIdx.x * 16 + sub;
    const int* rp; const uint2* cv; const u32* fin; u32* fout;
    if (blockIdx.y == 0){ rp=rpA; cv=cvA; fin=finA; fout=foutA; }
    else                { rp=rpB; cv=cvB; fin=finB; fout=foutB; }
    if (row >= M_SIMP) return;
    int s = rp[row], en = rp[row + 1];
    float a0=0,a1=0,a2=0,a3=0,a4=0,a5=0,a6=0,a7=0;
    int j = s;
    for (; j + 4 <= en; j += 4){
        uint2 q0 = cv[j], q1 = cv[j+1], q2 = cv[j+2], q3 = cv[j+3];
        uint4 g0 = *(const uint4*)(fin + (size_t)q0.x * 64 + l * 4);
        uint4 g1 = *(const uint4*)(fin + (size_t)q1.x * 64 + l * 4);
        uint4 g2 = *(const uint4*)(fin + (size_t)q2.x * 64 + l * 4);
        uint4 g3 = *(const uint4*)(fin + (size_t)q3.x * 64 + l * 4);
        float v0 = __uint_as_float(q0.y), v1 = __uint_as_float(q1.y);
        float v2 = __uint_as_float(q2.y), v3 = __uint_as_float(q3.y);
        a0 += v0*bf2f(g0.x&0xffffu) + v1*bf2f(g1.x&0xffffu) + v2*bf2f(g2.x&0xffffu) + v3*bf2f(g3.x&0xffffu);
        a1 += v0*bf2f(g0.x>>16)     + v1*bf2f(g1.x>>16)     + v2*bf2f(g2.x>>16)     + v3*bf2f(g3.x>>16);
        a2 += v0*bf2f(g0.y&0xffffu) + v1*bf2f(g1.y&0xffffu) + v2*bf2f(g2.y&0xffffu) + v3*bf2f(g3.y&0xffffu);
        a3 += v0*bf2f(g0.y>>16)     + v1*bf2f(g1.y>>16)     + v2*bf2f(g2.y>>16)     + v3*bf2f(g3.y>>16);
        a4 += v0*bf2f(g0.z&0xffffu) + v1*bf2f(g1.z&0xffffu) + v2*bf2f(g2.z&0xffffu) + v3*bf2f(g3.z&0xffffu);
        a5 += v0*bf2f(g0.z>>16)     + v1*bf2f(g1.z>>16)     + v2*bf2f(g2.z>>16)     + v3*bf2f(g3.z>>16);
        a6 += v0*bf2f(g0.w&0xffffu) + v1*bf2f(g1.w&0xffffu) + v2*bf2f(g2.w&0xffffu) + v3*bf2f(g3.w&0xffffu);
        a7 += v0*bf2f(g0.w>>16)     + v1*bf2f(g1.w>>16)     + v2*bf2f(g2.w>>16)     + v3*bf2f(g3.w>>16);
    }
    for (; j < en; j++){
        uint2 q = cv[j];
        float v = __uint_as_float(q.y);
        uint4 g = *(const uint4*)(fin + (size_t)q.x * 64 + l * 4);
        a0 += v*bf2f(g.x&0xffffu); a1 += v*bf2f(g.x>>16);
        a2 += v*bf2f(g.y&0xffffu); a3 += v*bf2f(g.y>>16);
        a4 += v*bf2f(g.z&0xffffu); a5 += v*bf2f(g.z>>16);
        a6 += v*bf2f(g.w&0xffffu); a7 += v*bf2f(g.w>>16);
    }
    uint4 o;
    o.x = f2bf(a0) | (f2bf(a1) << 16);
    o.y = f2bf(a2) | (f2bf(a3) << 16);
    o.z = f2bf(a4) | (f2bf(a5) << 16);
    o.w = f2bf(a6) | (f2bf(a7) << 16);
    *(uint4*)(fout + (size_t)row * 64 + l * 4) = o;
}

// ---------------- theta (o,i,k) fp32 -> Wb bf16 [km][o][i] packed u32 -------
// km slots: 0 -> theta_k0 + theta_k3 (both multiply F0), 1->k1, 2->k2, 3->k4, 4->k5
__global__ void k_wb(const float* __restrict__ theta, u32* __restrict__ Wb){
    int idx = blockIdx.x * 256 + threadIdx.x;
    if (idx < KM5 * 64 * 32){
        int km = idx >> 11;
        int r  = idx & 2047;
        int o  = r >> 5;
        int i2 = (r & 31) * 2;
        int k  = (km == 0) ? 0 : ((km < 3) ? km : km + 1);   // 0,1,2,4,5
        float lo = theta[o * 384 + i2 * 6 + k];
        float hi = theta[o * 384 + (i2 + 1) * 6 + k];
        if (km == 0){
            lo += theta[o * 384 + i2 * 6 + 3];
            hi += theta[o * 384 + (i2 + 1) * 6 + 3];
        }
        Wb[idx] = f2bf(lo) | (f2bf(hi) << 16);
    }
}

// ---------------- MFMA GEMM: LDS double-buffered staging --------------------
// Block: 64 m-rows x 64 o x both b. Per km: stage 64x256B F-tile into LDS via
// global_load_lds (fire-and-forget, no VGPR dest -> 16KB/block in flight).
// XOR swizzle (chunk ^= row&15) applied on the GLOBAL source during staging
// (LDS dest must stay linear) and on the ds_read address (involution).
__global__ __launch_bounds__(256, 4) void k_gemm(
    const u32* __restrict__ F0, const u32* __restrict__ F1, const u32* __restrict__ F2,
    const u32* __restrict__ F4, const u32* __restrict__ F5,
    const u32* __restrict__ Wb, const float* __restrict__ bias, float* __restrict__ out)
{
    __shared__ __align__(16) u32 sh[2][4096];   // 2 x 16 KB tiles
    int t    = threadIdx.x;
    int wave = t >> 6;
    int lane = t & 63;
    int q    = lane >> 4;
    int l16  = lane & 15;
    int bm   = blockIdx.x * 64;
    const u32* __restrict__ Fs[KM5] = {F0, F1, F2, F4, F5};

    // staging geometry (per thread, km-invariant)
    int rowbase  = t >> 4;                      // 0..15
    int srcc     = (t & 15) ^ ((t >> 4) & 15);  // swizzled source chunk-in-row
    int wavebase = (t & 192) * 4;               // wave*256 u32 (uniform per wave)

    f32x4 a00 = {0.f,0.f,0.f,0.f}, a10 = {0.f,0.f,0.f,0.f};
    f32x4 a20 = {0.f,0.f,0.f,0.f}, a30 = {0.f,0.f,0.f,0.f};
    f32x4 a01 = {0.f,0.f,0.f,0.f}, a11 = {0.f,0.f,0.f,0.f};
    f32x4 a21 = {0.f,0.f,0.f,0.f}, a31 = {0.f,0.f,0.f,0.f};

    int o_a = wave * 16 + l16;

    // W fragments for km=0 (rolling 1-ahead prefetch)
    short8 wc0 = *(const short8*)(Wb + (0 * 64 + o_a) * 32 + 0 * 16 + q * 4);
    short8 wc1 = *(const short8*)(Wb + (0 * 64 + o_a) * 32 + 1 * 16 + q * 4);

    // prologue: stage km=0
    #pragma unroll
    for (int i = 0; i < 4; ++i){
        const u32* g = Fs[0] + (size_t)(bm + i * 16 + rowbase) * 64 + srcc * 4;
        __builtin_amdgcn_global_load_lds(g, &sh[0][i * 1024 + wavebase], 16, 0, 0);
    }
    asm volatile("s_waitcnt vmcnt(0)" ::: "memory");
    __syncthreads();

    #pragma unroll
    for (int km = 0; km < KM5; ++km){
        short8 wn0 = wc0, wn1 = wc1;
        if (km < KM5 - 1){
            wn0 = *(const short8*)(Wb + ((km + 1) * 64 + o_a) * 32 + 0 * 16 + q * 4);
            wn1 = *(const short8*)(Wb + ((km + 1) * 64 + o_a) * 32 + 1 * 16 + q * 4);
            const u32* __restrict__ Fn = Fs[km + 1];
            u32* dst = &sh[(km + 1) & 1][0];
            #pragma unroll
            for (int i = 0; i < 4; ++i){
                const u32* g = Fn + (size_t)(bm + i * 16 + rowbase) * 64 + srcc * 4;
                __builtin_amdgcn_global_load_lds(g, dst + i * 1024 + wavebase, 16, 0, 0);
            }
        }

        const u32* Lb = &sh[km & 1][0];
        #pragma unroll
        for (int h = 0; h < 2; ++h){
            short8 wa = h ? wc1 : wc0;
            int c0 = ((h * 4 + q) ^ l16) * 4;        // b=0 swizzled col (u32 units)
            int c1 = ((8 + h * 4 + q) ^ l16) * 4;    // b=1
            #pragma unroll
            for (int ms = 0; ms < 4; ++ms){
                const u32* rp_ = Lb + ms * 1024 + l16 * 64;
                short8 b0 = *(const short8*)(rp_ + c0);
                short8 b1 = *(const short8*)(rp_ + c1);
                if (ms == 0){ a00 = __builtin_amdgcn_mfma_f32_16x16x32_bf16(wa, b0, a00, 0, 0, 0);
                              a01 = __builtin_amdgcn_mfma_f32_16x16x32_bf16(wa, b1, a01, 0, 0, 0); }
                if (ms == 1){ a10 = __builtin_amdgcn_mfma_f32_16x16x32_bf16(wa, b0, a10, 0, 0, 0);
                              a11 = __builtin_amdgcn_mfma_f32_16x16x32_bf16(wa, b1, a11, 0, 0, 0); }
                if (ms == 2){ a20 = __builtin_amdgcn_mfma_f32_16x16x32_bf16(wa, b0, a20, 0, 0, 0);
                              a21 = __builtin_amdgcn_mfma_f32_16x16x32_bf16(wa, b1, a21, 0, 0, 0); }
                if (ms == 3){ a30 = __builtin_amdgcn_mfma_f32_16x16x32_bf16(wa, b0, a30, 0, 0, 0);
                              a31 = __builtin_amdgcn_mfma_f32_16x16x32_bf16(wa, b1, a31, 0, 0, 0); }
            }
        }

        asm volatile("s_waitcnt vmcnt(0)" ::: "memory");
        __syncthreads();
        wc0 = wn0; wc1 = wn1;
    }

    int ob = wave * 16 + q * 4;
    float bv0 = bias[ob], bv1 = bias[ob+1], bv2 = bias[ob+2], bv3 = bias[ob+3];
    f32x4 accs0[4] = {a00, a10, a20, a30};
    f32x4 accs1[4] = {a01, a11, a21, a31};
    #pragma unroll
    for (int ms = 0; ms < 4; ms++){
        int gm = bm + ms * 16 + l16;
        if (gm < M_SIMP){
            size_t base0 = (size_t)(0 * 64 + ob) * M_SIMP + gm;
            size_t base1 = (size_t)(1 * 64 + ob) * M_SIMP + gm;
            out[base0             ] = accs0[ms][0] + bv0;
            out[base0 + 1ul*M_SIMP] = accs0[ms][1] + bv1;
            out[base0 + 2ul*M_SIMP] = accs0[ms][2] + bv2;
            out[base0 + 3ul*M_SIMP] = accs0[ms][3] + bv3;
            out[base1             ] = accs1[ms][0] + bv0;
            out[base1 + 1ul*M_SIMP] = accs1[ms][1] + bv1;
            out[base1 + 2ul*M_SIMP] = accs1[ms][2] + bv2;
            out[base1 + 3ul*M_SIMP] = accs1[ms][3] + bv3;
        }
    }
}

extern "C" void kernel_launch(void* const* d_in, const int* in_sizes, int n_in,
                              void* d_out, int out_size, void* d_ws, size_t ws_size,
                              hipStream_t stream)
{
    const int*   Ll_idx = (const int*)d_in[0];
    const float* Ll_val = (const float*)d_in[1];
    const int*   Lu_idx = (const int*)d_in[2];
    const float* Lu_val = (const float*)d_in[3];
    const float* x      = (const float*)d_in[4];
    const float* theta  = (const float*)d_in[5];
    const float* bias   = (const float*)d_in[6];
    float* out = (float*)d_out;

    char* ws = (char*)d_ws;
    size_t off = 0;
    auto take = [&](size_t bytes) -> char* {
        char* p = ws + off;
        off = (off + bytes + 255) & ~(size_t)255;
        return p;
    };
    const size_t FB = (size_t)MPAD * 64 * 4;
    u32* F0 = (u32*)take(FB);
    u32* F1 = (u32*)take(FB);
    u32* F2 = (u32*)take(FB);
    u32* F4 = (u32*)take(FB);
    u32* F5 = (u32*)take(FB);
    u32* Wb = (u32*)take((size_t)KM5 * 64 * 32 * 4);
    int* cnt_l = (int*)take((size_t)M_SIMP * 4);
    int* cnt_u = (int*)take((size_t)M_SIMP * 4);
    int* rp_l  = (int*)take((size_t)(M_SIMP + 1) * 4);
    int* rp_u  = (int*)take((size_t)(M_SIMP + 1) * 4);
    int* pe_l  = (int*)take((size_t)NNZV * 4);
    int* pe_u  = (int*)take((size_t)NNZV * 4);
    uint2* cv_l = (uint2*)take((size_t)NNZV * 8);
    uint2* cv_u = (uint2*)take((size_t)NNZV * 8);
    int* bs_l = (int*)take(512);
    int* bs_u = (int*)take(512);

    hipMemsetAsync(cnt_l, 0, (size_t)M_SIMP * 4, stream);
    hipMemsetAsync(cnt_u, 0, (size_t)M_SIMP * 4, stream);

    const int NBH = (NNZV + 255) / 256;       // 3125
    dim3 gh(NBH, 2);
    k_histpe<<<gh, 256, 0, stream>>>(Ll_idx, cnt_l, pe_l, Lu_idx, cnt_u, pe_u);

    const int NBS = (M_SIMP + 1023) / 1024;   // 98
    dim3 gs(NBS, 2);
    k_scan1<<<gs, 256, 0, stream>>>(cnt_l, rp_l, bs_l, cnt_u, rp_u, bs_u, M_SIMP);
    k_scan2<<<1, 64, 0, stream>>>(bs_l, bs_u, rp_l, rp_u, NBS);
    k_scan3<<<gs, 256, 0, stream>>>(rp_l, bs_l, rp_u, bs_u, M_SIMP);

    k_scatcv<<<gh, 256, 0, stream>>>(Ll_idx, Ll_val, pe_l, rp_l, cv_l,
                                     Lu_idx, Lu_val, pe_u, rp_u, cv_u);

    const int NBT = (M_SIMP + 63) / 64;       // 1563
    k_transpose<<<NBT, 256, 0, stream>>>(x, F0);
    k_wb<<<(KM5 * 64 * 32 + 255) / 256, 256, 0, stream>>>(theta, Wb);

    const int NBM = (M_SIMP + 15) / 16;       // 6250
    dim3 gm(NBM, 2);
    k_spmm<<<gm, 256, 0, stream>>>(rp_l, cv_l, F0, F1,
                                   rp_u, cv_u, F0, F4);
    k_spmm<<<gm, 256, 0, stream>>>(rp_l, cv_l, F1, F2,
                                   rp_u, cv_u, F4, F5);

    k_gemm<<<NBT, 256, 0, stream>>>(F0, F1, F2, F4, F5, Wb, bias, out);
}

// Round 5
// 403.349 us; speedup vs baseline: 1.2682x; 1.0194x over previous
//
#include <hip/hip_runtime.h>
#include <stdint.h>

#define M_SIMP 100000
#define MPAD   100064
#define NNZV   800000
#define KM5    5
#define NBH    3125     // NNZV/256
#define NBT    1563     // ceil(M/64)
#define NBW    40       // KM5*64*32/256

typedef unsigned int u32;
typedef __attribute__((ext_vector_type(8))) short short8;
typedef __attribute__((ext_vector_type(4))) float f32x4;

__device__ __forceinline__ float bf2f(u32 u){ return __uint_as_float(u << 16); }
__device__ __forceinline__ u32 f2bf(float f){
    u32 u = __float_as_uint(f);
    return (u + 0x7FFFu + ((u >> 16) & 1u)) >> 16;   // RNE
}

// ---------------- fused front: XCD-private histogram + transpose + wb -------
// hist: per-XCD privatized counts -> workgroup-scope atomics execute at the
// local L2 (no cross-XCD coherence needed since each copy is single-XCD).
// pe[e] = local_rank | (xcc<<24). Kernel-end L2 writeback publishes counts.
__global__ void k_front(const int* __restrict__ Ll_idx, const int* __restrict__ Lu_idx,
                        int* __restrict__ cnt8_l, int* __restrict__ cnt8_u,
                        u32* __restrict__ pe_l, u32* __restrict__ pe_u,
                        const float* __restrict__ x, u32* __restrict__ F0,
                        const float* __restrict__ theta, u32* __restrict__ Wb)
{
    __shared__ unsigned short s[64 * 130];
    int bid = blockIdx.x;
    int t   = threadIdx.x;

    if (bid < 2 * NBH){
        int lap = (bid >= NBH);
        const int* idx = lap ? Lu_idx : Ll_idx;
        int* cnt8      = lap ? cnt8_u : cnt8_l;
        u32* pe        = lap ? pe_u  : pe_l;
        int e = (bid - lap * NBH) * 256 + t;
        u32 xcc;
        asm volatile("s_getreg_b32 %0, hwreg(HW_REG_XCC_ID)" : "=s"(xcc));
        xcc &= 7u;
        if (e < NNZV){
            int r = idx[e];
            u32 p = __hip_atomic_fetch_add((u32*)&cnt8[xcc * M_SIMP + r], 1u,
                                           __ATOMIC_RELAXED, __HIP_MEMORY_SCOPE_WORKGROUP);
            pe[e] = p | (xcc << 24);
        }
    } else if (bid < 2 * NBH + NBT){
        // transpose x (B,C,M) fp32 -> F0 (M,128) bf16
        int m0 = (bid - 2 * NBH) * 64;
        int j  = t & 63;
        int r4 = t >> 6;
        #pragma unroll 4
        for (int it = 0; it < 32; ++it){
            int bc = it * 4 + r4;
            int m  = m0 + j;
            if (m < M_SIMP)
                s[j * 130 + bc] = (unsigned short)f2bf(x[(size_t)bc * M_SIMP + m]);
        }
        __syncthreads();
        #pragma unroll 4
        for (int it = 0; it < 16; ++it){
            int m  = it * 4 + r4;
            int gm = m0 + m;
            if (gm < M_SIMP){
                u32 lo = s[m * 130 + 2 * j];
                u32 hi = s[m * 130 + 2 * j + 1];
                F0[(size_t)gm * 64 + j] = lo | (hi << 16);
            }
        }
    } else {
        // theta (o,i,k) fp32 -> Wb bf16 [km][o][i]; km0 = k0+k3 fold
        int idx = (bid - 2 * NBH - NBT) * 256 + t;
        if (idx < KM5 * 64 * 32){
            int km = idx >> 11;
            int r  = idx & 2047;
            int o  = r >> 5;
            int i2 = (r & 31) * 2;
            int k  = (km == 0) ? 0 : ((km < 3) ? km : km + 1);   // 0,1,2,4,5
            float lo = theta[o * 384 + i2 * 6 + k];
            float hi = theta[o * 384 + (i2 + 1) * 6 + k];
            if (km == 0){
                lo += theta[o * 384 + i2 * 6 + 3];
                hi += theta[o * 384 + (i2 + 1) * 6 + 3];
            }
            Wb[idx] = f2bf(lo) | (f2bf(hi) << 16);
        }
    }
}

// ---------------- scan1: 8-copy merge + exclusive scan, 1024 rows/block -----
// cnt8[i][m] <- rp_partial(m) + sum of copies j<i  (in-place); out[m] = rp_partial.
__global__ void k_scan1(int* __restrict__ cnt0, int* __restrict__ out0, int* __restrict__ bs0,
                        int* __restrict__ cnt1, int* __restrict__ out1, int* __restrict__ bs1,
                        int n){
    int* cnt   = blockIdx.y ? cnt1 : cnt0;
    int* out   = blockIdx.y ? out1 : out0;
    int* bsums = blockIdx.y ? bs1 : bs0;
    __shared__ int s[256];
    int t = threadIdx.x;
    int base = blockIdx.x * 1024 + t * 4;
    int c[8][4];
    int tot[4] = {0,0,0,0};
    bool ok = (base < n);          // n % 4 == 0 -> whole group in-range
    if (ok){
        #pragma unroll
        for (int i = 0; i < 8; i++){
            int4 v = *(const int4*)(cnt + (size_t)i * M_SIMP + base);
            c[i][0]=v.x; c[i][1]=v.y; c[i][2]=v.z; c[i][3]=v.w;
            tot[0]+=v.x; tot[1]+=v.y; tot[2]+=v.z; tot[3]+=v.w;
        }
    }
    int sum = tot[0]+tot[1]+tot[2]+tot[3];
    s[t] = sum;
    __syncthreads();
    for (int off = 1; off < 256; off <<= 1){
        int x = (t >= off) ? s[t - off] : 0;
        __syncthreads();
        s[t] += x;
        __syncthreads();
    }
    int excl = s[t] - sum;
    if (t == 255) bsums[blockIdx.x] = s[255];
    if (ok){
        int ro[4];
        ro[0] = excl;
        ro[1] = ro[0] + tot[0];
        ro[2] = ro[1] + tot[1];
        ro[3] = ro[2] + tot[2];
        *(int4*)(out + base) = make_int4(ro[0], ro[1], ro[2], ro[3]);
        int p0=ro[0], p1=ro[1], p2=ro[2], p3=ro[3];
        #pragma unroll
        for (int i = 0; i < 8; i++){
            *(int4*)(cnt + (size_t)i * M_SIMP + base) = make_int4(p0, p1, p2, p3);
            p0 += c[i][0]; p1 += c[i][1]; p2 += c[i][2]; p3 += c[i][3];
        }
    }
}

__global__ void k_scan2(int* __restrict__ b0, int* __restrict__ b1,
                        int* __restrict__ rp0, int* __restrict__ rp1, int nb){
    int t = threadIdx.x;
    if (t < 2){
        int* bs = t ? b1 : b0;
        int run = 0;
        for (int i = 0; i < nb; i++){ int x = bs[i]; bs[i] = run; run += x; }
    }
    if (t == 2) rp0[M_SIMP] = NNZV;
    if (t == 3) rp1[M_SIMP] = NNZV;
}

// scan3: add block offset to rp AND all 8 cnt8 copies
__global__ void k_scan3(int* __restrict__ o0, const int* __restrict__ b0, int* __restrict__ c0,
                        int* __restrict__ o1, const int* __restrict__ b1, int* __restrict__ c1,
                        int n){
    int* out = blockIdx.y ? o1 : o0;
    const int* bsums = blockIdx.y ? b1 : b0;
    int* c8  = blockIdx.y ? c1 : c0;
    int base = blockIdx.x * 1024 + threadIdx.x * 4;
    int add = bsums[blockIdx.x];
    if (base < n){
        int4* po = (int4*)(out + base);
        int4 v = *po; v.x+=add; v.y+=add; v.z+=add; v.w+=add; *po = v;
        #pragma unroll
        for (int i = 0; i < 8; i++){
            int4* pc = (int4*)(c8 + (size_t)i * M_SIMP + base);
            int4 u = *pc; u.x+=add; u.y+=add; u.z+=add; u.w+=add; *pc = u;
        }
    }
}

// ---------------- scatter packed (col,val) into CSR order -------------------
// pos = cnt8[xcd][r] (= rp[r] + cross-copy base) + local rank
__global__ void k_scatcv(const int* __restrict__ i0, const float* __restrict__ v0,
                         const u32* __restrict__ pe0, const int* __restrict__ c8_0,
                         uint2* __restrict__ cv0,
                         const int* __restrict__ i1, const float* __restrict__ v1,
                         const u32* __restrict__ pe1, const int* __restrict__ c8_1,
                         uint2* __restrict__ cv1){
    int e = blockIdx.x * 256 + threadIdx.x;
    const int* idx   = blockIdx.y ? i1 : i0;
    const float* val = blockIdx.y ? v1 : v0;
    const u32* pe    = blockIdx.y ? pe1 : pe0;
    const int* c8    = blockIdx.y ? c8_1 : c8_0;
    uint2* cv        = blockIdx.y ? cv1 : cv0;
    if (e < NNZV){
        int r = idx[e];
        u32 pr = pe[e];
        int pos = c8[(size_t)(pr >> 24) * M_SIMP + r] + (int)(pr & 0xFFFFFFu);
        uint2 o;
        o.x = (u32)idx[NNZV + e];            // column
        o.y = __float_as_uint(val[e]);       // value bits
        cv[pos] = o;
    }
}

// ---------------- SpMM: sequential (col,val) + uint4 gathers ----------------
__global__ __launch_bounds__(256) void k_spmm(
    const int* __restrict__ rpA, const uint2* __restrict__ cvA,
    const u32* __restrict__ finA, u32* __restrict__ foutA,
    const int* __restrict__ rpB, const uint2* __restrict__ cvB,
    const u32* __restrict__ finB, u32* __restrict__ foutB)
{
    int t   = threadIdx.x;
    int sub = t >> 4;          // row slot 0..15
    int l   = t & 15;          // 8 channels per lane
    int row = blockIdx.x * 16 + sub;
    const int* rp; const uint2* cv; const u32* fin; u32* fout;
    if (blockIdx.y == 0){ rp=rpA; cv=cvA; fin=finA; fout=foutA; }
    else                { rp=rpB; cv=cvB; fin=finB; fout=foutB; }
    if (row >= M_SIMP) return;
    int s = rp[row], en = rp[row + 1];
    float a0=0,a1=0,a2=0,a3=0,a4=0,a5=0,a6=0,a7=0;
    int j = s;
    for (; j + 4 <= en; j += 4){
        uint2 q0 = cv[j], q1 = cv[j+1], q2 = cv[j+2], q3 = cv[j+3];
        uint4 g0 = *(const uint4*)(fin + (size_t)q0.x * 64 + l * 4);
        uint4 g1 = *(const uint4*)(fin + (size_t)q1.x * 64 + l * 4);
        uint4 g2 = *(const uint4*)(fin + (size_t)q2.x * 64 + l * 4);
        uint4 g3 = *(const uint4*)(fin + (size_t)q3.x * 64 + l * 4);
        float v0 = __uint_as_float(q0.y), v1 = __uint_as_float(q1.y);
        float v2 = __uint_as_float(q2.y), v3 = __uint_as_float(q3.y);
        a0 += v0*bf2f(g0.x&0xffffu) + v1*bf2f(g1.x&0xffffu) + v2*bf2f(g2.x&0xffffu) + v3*bf2f(g3.x&0xffffu);
        a1 += v0*bf2f(g0.x>>16)     + v1*bf2f(g1.x>>16)     + v2*bf2f(g2.x>>16)     + v3*bf2f(g3.x>>16);
        a2 += v0*bf2f(g0.y&0xffffu) + v1*bf2f(g1.y&0xffffu) + v2*bf2f(g2.y&0xffffu) + v3*bf2f(g3.y&0xffffu);
        a3 += v0*bf2f(g0.y>>16)     + v1*bf2f(g1.y>>16)     + v2*bf2f(g2.y>>16)     + v3*bf2f(g3.y>>16);
        a4 += v0*bf2f(g0.z&0xffffu) + v1*bf2f(g1.z&0xffffu) + v2*bf2f(g2.z&0xffffu) + v3*bf2f(g3.z&0xffffu);
        a5 += v0*bf2f(g0.z>>16)     + v1*bf2f(g1.z>>16)     + v2*bf2f(g2.z>>16)     + v3*bf2f(g3.z>>16);
        a6 += v0*bf2f(g0.w&0xffffu) + v1*bf2f(g1.w&0xffffu) + v2*bf2f(g2.w&0xffffu) + v3*bf2f(g3.w&0xffffu);
        a7 += v0*bf2f(g0.w>>16)     + v1*bf2f(g1.w>>16)     + v2*bf2f(g2.w>>16)     + v3*bf2f(g3.w>>16);
    }
    for (; j < en; j++){
        uint2 q = cv[j];
        float v = __uint_as_float(q.y);
        uint4 g = *(const uint4*)(fin + (size_t)q.x * 64 + l * 4);
        a0 += v*bf2f(g.x&0xffffu); a1 += v*bf2f(g.x>>16);
        a2 += v*bf2f(g.y&0xffffu); a3 += v*bf2f(g.y>>16);
        a4 += v*bf2f(g.z&0xffffu); a5 += v*bf2f(g.z>>16);
        a6 += v*bf2f(g.w&0xffffu); a7 += v*bf2f(g.w>>16);
    }
    uint4 o;
    o.x = f2bf(a0) | (f2bf(a1) << 16);
    o.y = f2bf(a2) | (f2bf(a3) << 16);
    o.z = f2bf(a4) | (f2bf(a5) << 16);
    o.w = f2bf(a6) | (f2bf(a7) << 16);
    *(uint4*)(fout + (size_t)row * 64 + l * 4) = o;
}

// ---------------- MFMA GEMM: LDS double-buffered staging --------------------
__global__ __launch_bounds__(256, 4) void k_gemm(
    const u32* __restrict__ F0, const u32* __restrict__ F1, const u32* __restrict__ F2,
    const u32* __restrict__ F4, const u32* __restrict__ F5,
    const u32* __restrict__ Wb, const float* __restrict__ bias, float* __restrict__ out)
{
    __shared__ __align__(16) u32 sh[2][4096];   // 2 x 16 KB tiles
    int t    = threadIdx.x;
    int wave = t >> 6;
    int lane = t & 63;
    int q    = lane >> 4;
    int l16  = lane & 15;
    int bm   = blockIdx.x * 64;
    const u32* __restrict__ Fs[KM5] = {F0, F1, F2, F4, F5};

    int rowbase  = t >> 4;                      // 0..15
    int srcc     = (t & 15) ^ ((t >> 4) & 15);  // swizzled source chunk-in-row
    int wavebase = (t & 192) * 4;               // wave*256 u32

    f32x4 a00 = {0.f,0.f,0.f,0.f}, a10 = {0.f,0.f,0.f,0.f};
    f32x4 a20 = {0.f,0.f,0.f,0.f}, a30 = {0.f,0.f,0.f,0.f};
    f32x4 a01 = {0.f,0.f,0.f,0.f}, a11 = {0.f,0.f,0.f,0.f};
    f32x4 a21 = {0.f,0.f,0.f,0.f}, a31 = {0.f,0.f,0.f,0.f};

    int o_a = wave * 16 + l16;

    short8 wc0 = *(const short8*)(Wb + (0 * 64 + o_a) * 32 + 0 * 16 + q * 4);
    short8 wc1 = *(const short8*)(Wb + (0 * 64 + o_a) * 32 + 1 * 16 + q * 4);

    #pragma unroll
    for (int i = 0; i < 4; ++i){
        const u32* g = Fs[0] + (size_t)(bm + i * 16 + rowbase) * 64 + srcc * 4;
        __builtin_amdgcn_global_load_lds(g, &sh[0][i * 1024 + wavebase], 16, 0, 0);
    }
    asm volatile("s_waitcnt vmcnt(0)" ::: "memory");
    __syncthreads();

    #pragma unroll
    for (int km = 0; km < KM5; ++km){
        short8 wn0 = wc0, wn1 = wc1;
        if (km < KM5 - 1){
            wn0 = *(const short8*)(Wb + ((km + 1) * 64 + o_a) * 32 + 0 * 16 + q * 4);
            wn1 = *(const short8*)(Wb + ((km + 1) * 64 + o_a) * 32 + 1 * 16 + q * 4);
            const u32* __restrict__ Fn = Fs[km + 1];
            u32* dst = &sh[(km + 1) & 1][0];
            #pragma unroll
            for (int i = 0; i < 4; ++i){
                const u32* g = Fn + (size_t)(bm + i * 16 + rowbase) * 64 + srcc * 4;
                __builtin_amdgcn_global_load_lds(g, dst + i * 1024 + wavebase, 16, 0, 0);
            }
        }

        const u32* Lb = &sh[km & 1][0];
        #pragma unroll
        for (int h = 0; h < 2; ++h){
            short8 wa = h ? wc1 : wc0;
            int c0 = ((h * 4 + q) ^ l16) * 4;        // b=0 swizzled col (u32 units)
            int c1 = ((8 + h * 4 + q) ^ l16) * 4;    // b=1
            #pragma unroll
            for (int ms = 0; ms < 4; ++ms){
                const u32* rp_ = Lb + ms * 1024 + l16 * 64;
                short8 b0 = *(const short8*)(rp_ + c0);
                short8 b1 = *(const short8*)(rp_ + c1);
                if (ms == 0){ a00 = __builtin_amdgcn_mfma_f32_16x16x32_bf16(wa, b0, a00, 0, 0, 0);
                              a01 = __builtin_amdgcn_mfma_f32_16x16x32_bf16(wa, b1, a01, 0, 0, 0); }
                if (ms == 1){ a10 = __builtin_amdgcn_mfma_f32_16x16x32_bf16(wa, b0, a10, 0, 0, 0);
                              a11 = __builtin_amdgcn_mfma_f32_16x16x32_bf16(wa, b1, a11, 0, 0, 0); }
                if (ms == 2){ a20 = __builtin_amdgcn_mfma_f32_16x16x32_bf16(wa, b0, a20, 0, 0, 0);
                              a21 = __builtin_amdgcn_mfma_f32_16x16x32_bf16(wa, b1, a21, 0, 0, 0); }
                if (ms == 3){ a30 = __builtin_amdgcn_mfma_f32_16x16x32_bf16(wa, b0, a30, 0, 0, 0);
                              a31 = __builtin_amdgcn_mfma_f32_16x16x32_bf16(wa, b1, a31, 0, 0, 0); }
            }
        }

        asm volatile("s_waitcnt vmcnt(0)" ::: "memory");
        __syncthreads();
        wc0 = wn0; wc1 = wn1;
    }

    int ob = wave * 16 + q * 4;
    float bv0 = bias[ob], bv1 = bias[ob+1], bv2 = bias[ob+2], bv3 = bias[ob+3];
    f32x4 accs0[4] = {a00, a10, a20, a30};
    f32x4 accs1[4] = {a01, a11, a21, a31};
    #pragma unroll
    for (int ms = 0; ms < 4; ms++){
        int gm = bm + ms * 16 + l16;
        if (gm < M_SIMP){
            size_t base0 = (size_t)(0 * 64 + ob) * M_SIMP + gm;
            size_t base1 = (size_t)(1 * 64 + ob) * M_SIMP + gm;
            out[base0             ] = accs0[ms][0] + bv0;
            out[base0 + 1ul*M_SIMP] = accs0[ms][1] + bv1;
            out[base0 + 2ul*M_SIMP] = accs0[ms][2] + bv2;
            out[base0 + 3ul*M_SIMP] = accs0[ms][3] + bv3;
            out[base1             ] = accs1[ms][0] + bv0;
            out[base1 + 1ul*M_SIMP] = accs1[ms][1] + bv1;
            out[base1 + 2ul*M_SIMP] = accs1[ms][2] + bv2;
            out[base1 + 3ul*M_SIMP] = accs1[ms][3] + bv3;
        }
    }
}

extern "C" void kernel_launch(void* const* d_in, const int* in_sizes, int n_in,
                              void* d_out, int out_size, void* d_ws, size_t ws_size,
                              hipStream_t stream)
{
    const int*   Ll_idx = (const int*)d_in[0];
    const float* Ll_val = (const float*)d_in[1];
    const int*   Lu_idx = (const int*)d_in[2];
    const float* Lu_val = (const float*)d_in[3];
    const float* x      = (const float*)d_in[4];
    const float* theta  = (const float*)d_in[5];
    const float* bias   = (const float*)d_in[6];
    float* out = (float*)d_out;

    char* ws = (char*)d_ws;
    size_t off = 0;
    auto take = [&](size_t bytes) -> char* {
        char* p = ws + off;
        off = (off + bytes + 255) & ~(size_t)255;
        return p;
    };
    const size_t FB = (size_t)MPAD * 64 * 4;
    u32* F0 = (u32*)take(FB);
    u32* F1 = (u32*)take(FB);
    u32* F2 = (u32*)take(FB);
    u32* F4 = (u32*)take(FB);
    u32* F5 = (u32*)take(FB);
    u32* Wb = (u32*)take((size_t)KM5 * 64 * 32 * 4);
    int* cnt8_l = (int*)take((size_t)8 * M_SIMP * 4);
    int* cnt8_u = (int*)take((size_t)8 * M_SIMP * 4);
    int* rp_l  = (int*)take((size_t)(M_SIMP + 1) * 4);
    int* rp_u  = (int*)take((size_t)(M_SIMP + 1) * 4);
    u32* pe_l  = (u32*)take((size_t)NNZV * 4);
    u32* pe_u  = (u32*)take((size_t)NNZV * 4);
    uint2* cv_l = (uint2*)take((size_t)NNZV * 8);
    uint2* cv_u = (uint2*)take((size_t)NNZV * 8);
    int* bs_l = (int*)take(512);
    int* bs_u = (int*)take(512);

    hipMemsetAsync(cnt8_l, 0, (size_t)8 * M_SIMP * 4, stream);
    hipMemsetAsync(cnt8_u, 0, (size_t)8 * M_SIMP * 4, stream);

    // fused: XCD-private hist + transpose + wb
    k_front<<<2 * NBH + NBT + NBW, 256, 0, stream>>>(
        Ll_idx, Lu_idx, cnt8_l, cnt8_u, pe_l, pe_u, x, F0, theta, Wb);

    const int NBS = (M_SIMP + 1023) / 1024;   // 98
    dim3 gs(NBS, 2);
    k_scan1<<<gs, 256, 0, stream>>>(cnt8_l, rp_l, bs_l, cnt8_u, rp_u, bs_u, M_SIMP);
    k_scan2<<<1, 64, 0, stream>>>(bs_l, bs_u, rp_l, rp_u, NBS);
    k_scan3<<<gs, 256, 0, stream>>>(rp_l, bs_l, cnt8_l, rp_u, bs_u, cnt8_u, M_SIMP);

    dim3 gh(NBH, 2);
    k_scatcv<<<gh, 256, 0, stream>>>(Ll_idx, Ll_val, pe_l, cnt8_l, cv_l,
                                     Lu_idx, Lu_val, pe_u, cnt8_u, cv_u);

    const int NBM = (M_SIMP + 15) / 16;       // 6250
    dim3 gm(NBM, 2);
    k_spmm<<<gm, 256, 0, stream>>>(rp_l, cv_l, F0, F1,
                                   rp_u, cv_u, F0, F4);
    k_spmm<<<gm, 256, 0, stream>>>(rp_l, cv_l, F1, F2,
                                   rp_u, cv_u, F4, F5);

    k_gemm<<<NBT, 256, 0, stream>>>(F0, F1, F2, F4, F5, Wb, bias, out);
}

// Round 6
// 386.510 us; speedup vs baseline: 1.3234x; 1.0436x over previous
//
#include <hip/hip_runtime.h>
#include <stdint.h>

#define M_SIMP 100000
#define MPAD   100064
#define NNZV   800000
#define KM5    5
#define NBH    3125     // NNZV/256
#define NBT    1563     // ceil(M/64)
#define NBW    40       // KM5*64*32/256
#define NBF    8015     // 5*1603: 4/5 hist (6412 slots >= 6250), 1/5 other (1603 = NBT+NBW)

typedef unsigned int u32;
typedef __attribute__((ext_vector_type(8))) short short8;
typedef __attribute__((ext_vector_type(4))) float f32x4;

__device__ __forceinline__ float bf2f(u32 u){ return __uint_as_float(u << 16); }
__device__ __forceinline__ u32 f2bf(float f){
    u32 u = __float_as_uint(f);
    return (u + 0x7FFFu + ((u >> 16) & 1u)) >> 16;   // RNE
}

// ---------------- fused front: striped roles ---------------------------------
// bid%5 < 4 -> histogram (atomic-bound, idle pipes); bid%5==4 -> transpose/wb
// (streaming). Striping keeps a ~80/20 resident mix so streaming work hides
// inside the atomic stalls instead of serializing after them.
__global__ void k_front(const int* __restrict__ Ll_idx, const int* __restrict__ Lu_idx,
                        int* __restrict__ cnt8_l, int* __restrict__ cnt8_u,
                        u32* __restrict__ pe_l, u32* __restrict__ pe_u,
                        const float* __restrict__ x, u32* __restrict__ F0,
                        const float* __restrict__ theta, u32* __restrict__ Wb)
{
    __shared__ unsigned short s[64 * 130];
    int bid = blockIdx.x;
    int t   = threadIdx.x;
    int r5  = bid % 5;
    int g5  = bid / 5;          // 0..1602

    if (r5 < 4){
        int h = g5 * 4 + r5;    // 0..6411
        if (h >= 2 * NBH) return;
        int lap = (h >= NBH);
        const int* idx = lap ? Lu_idx : Ll_idx;
        int* cnt8      = lap ? cnt8_u : cnt8_l;
        u32* pe        = lap ? pe_u  : pe_l;
        int e = (h - lap * NBH) * 256 + t;
        u32 xcc;
        asm volatile("s_getreg_b32 %0, hwreg(HW_REG_XCC_ID)" : "=s"(xcc));
        xcc &= 7u;
        if (e < NNZV){
            int r = idx[e];
            u32 p = __hip_atomic_fetch_add((u32*)&cnt8[xcc * M_SIMP + r], 1u,
                                           __ATOMIC_RELAXED, __HIP_MEMORY_SCOPE_WORKGROUP);
            pe[e] = p | (xcc << 24);
        }
    } else if (g5 < NBT){
        // transpose x (B,C,M) fp32 -> F0 (M,128) bf16
        int m0 = g5 * 64;
        int j  = t & 63;
        int r4 = t >> 6;
        #pragma unroll 4
        for (int it = 0; it < 32; ++it){
            int bc = it * 4 + r4;
            int m  = m0 + j;
            if (m < M_SIMP)
                s[j * 130 + bc] = (unsigned short)f2bf(x[(size_t)bc * M_SIMP + m]);
        }
        __syncthreads();
        #pragma unroll 4
        for (int it = 0; it < 16; ++it){
            int m  = it * 4 + r4;
            int gm = m0 + m;
            if (gm < M_SIMP){
                u32 lo = s[m * 130 + 2 * j];
                u32 hi = s[m * 130 + 2 * j + 1];
                F0[(size_t)gm * 64 + j] = lo | (hi << 16);
            }
        }
    } else {
        // theta (o,i,k) fp32 -> Wb bf16 [km][o][i]; km0 = k0+k3 fold
        int idx = (g5 - NBT) * 256 + t;
        if (idx < KM5 * 64 * 32){
            int km = idx >> 11;
            int r  = idx & 2047;
            int o  = r >> 5;
            int i2 = (r & 31) * 2;
            int k  = (km == 0) ? 0 : ((km < 3) ? km : km + 1);   // 0,1,2,4,5
            float lo = theta[o * 384 + i2 * 6 + k];
            float hi = theta[o * 384 + (i2 + 1) * 6 + k];
            if (km == 0){
                lo += theta[o * 384 + i2 * 6 + 3];
                hi += theta[o * 384 + (i2 + 1) * 6 + 3];
            }
            Wb[idx] = f2bf(lo) | (f2bf(hi) << 16);
        }
    }
}

// ---------------- scan1: 8-copy merge + exclusive scan, 1024 rows/block -----
// cnt8[i][m] <- rp_partial(m) + sum of copies j<i  (in-place); out[m] = rp_partial.
// bsums[b] = RAW block total (scan3 computes its own prefix).
__global__ void k_scan1(int* __restrict__ cnt0, int* __restrict__ out0, int* __restrict__ bs0,
                        int* __restrict__ cnt1, int* __restrict__ out1, int* __restrict__ bs1,
                        int n){
    int* cnt   = blockIdx.y ? cnt1 : cnt0;
    int* out   = blockIdx.y ? out1 : out0;
    int* bsums = blockIdx.y ? bs1 : bs0;
    __shared__ int s[256];
    int t = threadIdx.x;
    int base = blockIdx.x * 1024 + t * 4;
    int c[8][4];
    int tot[4] = {0,0,0,0};
    bool ok = (base < n);          // n % 4 == 0 -> whole group in-range
    if (ok){
        #pragma unroll
        for (int i = 0; i < 8; i++){
            int4 v = *(const int4*)(cnt + (size_t)i * M_SIMP + base);
            c[i][0]=v.x; c[i][1]=v.y; c[i][2]=v.z; c[i][3]=v.w;
            tot[0]+=v.x; tot[1]+=v.y; tot[2]+=v.z; tot[3]+=v.w;
        }
    }
    int sum = tot[0]+tot[1]+tot[2]+tot[3];
    s[t] = sum;
    __syncthreads();
    for (int off = 1; off < 256; off <<= 1){
        int x = (t >= off) ? s[t - off] : 0;
        __syncthreads();
        s[t] += x;
        __syncthreads();
    }
    int excl = s[t] - sum;
    if (t == 255) bsums[blockIdx.x] = s[255];
    if (ok){
        int ro[4];
        ro[0] = excl;
        ro[1] = ro[0] + tot[0];
        ro[2] = ro[1] + tot[1];
        ro[3] = ro[2] + tot[2];
        *(int4*)(out + base) = make_int4(ro[0], ro[1], ro[2], ro[3]);
        int p0=ro[0], p1=ro[1], p2=ro[2], p3=ro[3];
        #pragma unroll
        for (int i = 0; i < 8; i++){
            *(int4*)(cnt + (size_t)i * M_SIMP + base) = make_int4(p0, p1, p2, p3);
            p0 += c[i][0]; p1 += c[i][1]; p2 += c[i][2]; p3 += c[i][3];
        }
    }
}

// scan3: per-block prefix of raw bsums (LDS tree) + add to rp and all 8 copies.
// block (0,y) thread 255 also writes rp[M] = NNZV (replaces old scan2).
__global__ void k_scan3(int* __restrict__ o0, const int* __restrict__ b0, int* __restrict__ c0,
                        int* __restrict__ o1, const int* __restrict__ b1, int* __restrict__ c1,
                        int n, int nb){
    int* out = blockIdx.y ? o1 : o0;
    const int* bsums = blockIdx.y ? b1 : b0;
    int* c8  = blockIdx.y ? c1 : c0;
    __shared__ int sb[256];
    int t = threadIdx.x;
    sb[t] = (t < (int)blockIdx.x && t < nb) ? bsums[t] : 0;
    __syncthreads();
    #pragma unroll
    for (int off = 128; off > 0; off >>= 1){
        if (t < off) sb[t] += sb[t + off];
        __syncthreads();
    }
    int add = sb[0];
    if (t == 255 && blockIdx.x == 0) out[n] = NNZV;   // rp[M]
    int base = blockIdx.x * 1024 + t * 4;
    if (base < n){
        int4* po = (int4*)(out + base);
        int4 v = *po; v.x+=add; v.y+=add; v.z+=add; v.w+=add; *po = v;
        #pragma unroll
        for (int i = 0; i < 8; i++){
            int4* pc = (int4*)(c8 + (size_t)i * M_SIMP + base);
            int4 u = *pc; u.x+=add; u.y+=add; u.z+=add; u.w+=add; *pc = u;
        }
    }
}

// ---------------- scatter packed (col,val) into CSR order -------------------
// pos = cnt8[xcd][r] (= rp[r] + cross-copy base) + local rank
__global__ void k_scatcv(const int* __restrict__ i0, const float* __restrict__ v0,
                         const u32* __restrict__ pe0, const int* __restrict__ c8_0,
                         uint2* __restrict__ cv0,
                         const int* __restrict__ i1, const float* __restrict__ v1,
                         const u32* __restrict__ pe1, const int* __restrict__ c8_1,
                         uint2* __restrict__ cv1){
    int e = blockIdx.x * 256 + threadIdx.x;
    const int* idx   = blockIdx.y ? i1 : i0;
    const float* val = blockIdx.y ? v1 : v0;
    const u32* pe    = blockIdx.y ? pe1 : pe0;
    const int* c8    = blockIdx.y ? c8_1 : c8_0;
    uint2* cv        = blockIdx.y ? cv1 : cv0;
    if (e < NNZV){
        int r = idx[e];
        u32 pr = pe[e];
        int pos = c8[(size_t)(pr >> 24) * M_SIMP + r] + (int)(pr & 0xFFFFFFu);
        uint2 o;
        o.x = (u32)idx[NNZV + e];            // column
        o.y = __float_as_uint(val[e]);       // value bits
        cv[pos] = o;
    }
}

// ---------------- SpMM: sequential (col,val) + uint4 gathers ----------------
__global__ __launch_bounds__(256) void k_spmm(
    const int* __restrict__ rpA, const uint2* __restrict__ cvA,
    const u32* __restrict__ finA, u32* __restrict__ foutA,
    const int* __restrict__ rpB, const uint2* __restrict__ cvB,
    const u32* __restrict__ finB, u32* __restrict__ foutB)
{
    int t   = threadIdx.x;
    int sub = t >> 4;          // row slot 0..15
    int l   = t & 15;          // 8 channels per lane
    int row = blockIdx.x * 16 + sub;
    const int* rp; const uint2* cv; const u32* fin; u32* fout;
    if (blockIdx.y == 0){ rp=rpA; cv=cvA; fin=finA; fout=foutA; }
    else                { rp=rpB; cv=cvB; fin=finB; fout=foutB; }
    if (row >= M_SIMP) return;
    int s = rp[row], en = rp[row + 1];
    float a0=0,a1=0,a2=0,a3=0,a4=0,a5=0,a6=0,a7=0;
    int j = s;
    for (; j + 4 <= en; j += 4){
        uint2 q0 = cv[j], q1 = cv[j+1], q2 = cv[j+2], q3 = cv[j+3];
        uint4 g0 = *(const uint4*)(fin + (size_t)q0.x * 64 + l * 4);
        uint4 g1 = *(const uint4*)(fin + (size_t)q1.x * 64 + l * 4);
        uint4 g2 = *(const uint4*)(fin + (size_t)q2.x * 64 + l * 4);
        uint4 g3 = *(const uint4*)(fin + (size_t)q3.x * 64 + l * 4);
        float v0 = __uint_as_float(q0.y), v1 = __uint_as_float(q1.y);
        float v2 = __uint_as_float(q2.y), v3 = __uint_as_float(q3.y);
        a0 += v0*bf2f(g0.x&0xffffu) + v1*bf2f(g1.x&0xffffu) + v2*bf2f(g2.x&0xffffu) + v3*bf2f(g3.x&0xffffu);
        a1 += v0*bf2f(g0.x>>16)     + v1*bf2f(g1.x>>16)     + v2*bf2f(g2.x>>16)     + v3*bf2f(g3.x>>16);
        a2 += v0*bf2f(g0.y&0xffffu) + v1*bf2f(g1.y&0xffffu) + v2*bf2f(g2.y&0xffffu) + v3*bf2f(g3.y&0xffffu);
        a3 += v0*bf2f(g0.y>>16)     + v1*bf2f(g1.y>>16)     + v2*bf2f(g2.y>>16)     + v3*bf2f(g3.y>>16);
        a4 += v0*bf2f(g0.z&0xffffu) + v1*bf2f(g1.z&0xffffu) + v2*bf2f(g2.z&0xffffu) + v3*bf2f(g3.z&0xffffu);
        a5 += v0*bf2f(g0.z>>16)     + v1*bf2f(g1.z>>16)     + v2*bf2f(g2.z>>16)     + v3*bf2f(g3.z>>16);
        a6 += v0*bf2f(g0.w&0xffffu) + v1*bf2f(g1.w&0xffffu) + v2*bf2f(g2.w&0xffffu) + v3*bf2f(g3.w&0xffffu);
        a7 += v0*bf2f(g0.w>>16)     + v1*bf2f(g1.w>>16)     + v2*bf2f(g2.w>>16)     + v3*bf2f(g3.w>>16);
    }
    for (; j < en; j++){
        uint2 q = cv[j];
        float v = __uint_as_float(q.y);
        uint4 g = *(const uint4*)(fin + (size_t)q.x * 64 + l * 4);
        a0 += v*bf2f(g.x&0xffffu); a1 += v*bf2f(g.x>>16);
        a2 += v*bf2f(g.y&0xffffu); a3 += v*bf2f(g.y>>16);
        a4 += v*bf2f(g.z&0xffffu); a5 += v*bf2f(g.z>>16);
        a6 += v*bf2f(g.w&0xffffu); a7 += v*bf2f(g.w>>16);
    }
    uint4 o;
    o.x = f2bf(a0) | (f2bf(a1) << 16);
    o.y = f2bf(a2) | (f2bf(a3) << 16);
    o.z = f2bf(a4) | (f2bf(a5) << 16);
    o.w = f2bf(a6) | (f2bf(a7) << 16);
    *(uint4*)(fout + (size_t)row * 64 + l * 4) = o;
}

// ---------------- MFMA GEMM: LDS double-buffered staging --------------------
__global__ __launch_bounds__(256, 4) void k_gemm(
    const u32* __restrict__ F0, const u32* __restrict__ F1, const u32* __restrict__ F2,
    const u32* __restrict__ F4, const u32* __restrict__ F5,
    const u32* __restrict__ Wb, const float* __restrict__ bias, float* __restrict__ out)
{
    __shared__ __align__(16) u32 sh[2][4096];   // 2 x 16 KB tiles
    int t    = threadIdx.x;
    int wave = t >> 6;
    int lane = t & 63;
    int q    = lane >> 4;
    int l16  = lane & 15;
    int bm   = blockIdx.x * 64;
    const u32* __restrict__ Fs[KM5] = {F0, F1, F2, F4, F5};

    int rowbase  = t >> 4;                      // 0..15
    int srcc     = (t & 15) ^ ((t >> 4) & 15);  // swizzled source chunk-in-row
    int wavebase = (t & 192) * 4;               // wave*256 u32

    f32x4 a00 = {0.f,0.f,0.f,0.f}, a10 = {0.f,0.f,0.f,0.f};
    f32x4 a20 = {0.f,0.f,0.f,0.f}, a30 = {0.f,0.f,0.f,0.f};
    f32x4 a01 = {0.f,0.f,0.f,0.f}, a11 = {0.f,0.f,0.f,0.f};
    f32x4 a21 = {0.f,0.f,0.f,0.f}, a31 = {0.f,0.f,0.f,0.f};

    int o_a = wave * 16 + l16;

    short8 wc0 = *(const short8*)(Wb + (0 * 64 + o_a) * 32 + 0 * 16 + q * 4);
    short8 wc1 = *(const short8*)(Wb + (0 * 64 + o_a) * 32 + 1 * 16 + q * 4);

    #pragma unroll
    for (int i = 0; i < 4; ++i){
        const u32* g = Fs[0] + (size_t)(bm + i * 16 + rowbase) * 64 + srcc * 4;
        __builtin_amdgcn_global_load_lds(g, &sh[0][i * 1024 + wavebase], 16, 0, 0);
    }
    asm volatile("s_waitcnt vmcnt(0)" ::: "memory");
    __syncthreads();

    #pragma unroll
    for (int km = 0; km < KM5; ++km){
        short8 wn0 = wc0, wn1 = wc1;
        if (km < KM5 - 1){
            wn0 = *(const short8*)(Wb + ((km + 1) * 64 + o_a) * 32 + 0 * 16 + q * 4);
            wn1 = *(const short8*)(Wb + ((km + 1) * 64 + o_a) * 32 + 1 * 16 + q * 4);
            const u32* __restrict__ Fn = Fs[km + 1];
            u32* dst = &sh[(km + 1) & 1][0];
            #pragma unroll
            for (int i = 0; i < 4; ++i){
                const u32* g = Fn + (size_t)(bm + i * 16 + rowbase) * 64 + srcc * 4;
                __builtin_amdgcn_global_load_lds(g, dst + i * 1024 + wavebase, 16, 0, 0);
            }
        }

        const u32* Lb = &sh[km & 1][0];
        #pragma unroll
        for (int h = 0; h < 2; ++h){
            short8 wa = h ? wc1 : wc0;
            int c0 = ((h * 4 + q) ^ l16) * 4;        // b=0 swizzled col (u32 units)
            int c1 = ((8 + h * 4 + q) ^ l16) * 4;    // b=1
            #pragma unroll
            for (int ms = 0; ms < 4; ++ms){
                const u32* rp_ = Lb + ms * 1024 + l16 * 64;
                short8 b0 = *(const short8*)(rp_ + c0);
                short8 b1 = *(const short8*)(rp_ + c1);
                if (ms == 0){ a00 = __builtin_amdgcn_mfma_f32_16x16x32_bf16(wa, b0, a00, 0, 0, 0);
                              a01 = __builtin_amdgcn_mfma_f32_16x16x32_bf16(wa, b1, a01, 0, 0, 0); }
                if (ms == 1){ a10 = __builtin_amdgcn_mfma_f32_16x16x32_bf16(wa, b0, a10, 0, 0, 0);
                              a11 = __builtin_amdgcn_mfma_f32_16x16x32_bf16(wa, b1, a11, 0, 0, 0); }
                if (ms == 2){ a20 = __builtin_amdgcn_mfma_f32_16x16x32_bf16(wa, b0, a20, 0, 0, 0);
                              a21 = __builtin_amdgcn_mfma_f32_16x16x32_bf16(wa, b1, a21, 0, 0, 0); }
                if (ms == 3){ a30 = __builtin_amdgcn_mfma_f32_16x16x32_bf16(wa, b0, a30, 0, 0, 0);
                              a31 = __builtin_amdgcn_mfma_f32_16x16x32_bf16(wa, b1, a31, 0, 0, 0); }
            }
        }

        asm volatile("s_waitcnt vmcnt(0)" ::: "memory");
        __syncthreads();
        wc0 = wn0; wc1 = wn1;
    }

    int ob = wave * 16 + q * 4;
    float bv0 = bias[ob], bv1 = bias[ob+1], bv2 = bias[ob+2], bv3 = bias[ob+3];
    f32x4 accs0[4] = {a00, a10, a20, a30};
    f32x4 accs1[4] = {a01, a11, a21, a31};
    #pragma unroll
    for (int ms = 0; ms < 4; ms++){
        int gm = bm + ms * 16 + l16;
        if (gm < M_SIMP){
            size_t base0 = (size_t)(0 * 64 + ob) * M_SIMP + gm;
            size_t base1 = (size_t)(1 * 64 + ob) * M_SIMP + gm;
            out[base0             ] = accs0[ms][0] + bv0;
            out[base0 + 1ul*M_SIMP] = accs0[ms][1] + bv1;
            out[base0 + 2ul*M_SIMP] = accs0[ms][2] + bv2;
            out[base0 + 3ul*M_SIMP] = accs0[ms][3] + bv3;
            out[base1             ] = accs1[ms][0] + bv0;
            out[base1 + 1ul*M_SIMP] = accs1[ms][1] + bv1;
            out[base1 + 2ul*M_SIMP] = accs1[ms][2] + bv2;
            out[base1 + 3ul*M_SIMP] = accs1[ms][3] + bv3;
        }
    }
}

extern "C" void kernel_launch(void* const* d_in, const int* in_sizes, int n_in,
                              void* d_out, int out_size, void* d_ws, size_t ws_size,
                              hipStream_t stream)
{
    const int*   Ll_idx = (const int*)d_in[0];
    const float* Ll_val = (const float*)d_in[1];
    const int*   Lu_idx = (const int*)d_in[2];
    const float* Lu_val = (const float*)d_in[3];
    const float* x      = (const float*)d_in[4];
    const float* theta  = (const float*)d_in[5];
    const float* bias   = (const float*)d_in[6];
    float* out = (float*)d_out;

    char* ws = (char*)d_ws;
    size_t off = 0;
    auto take = [&](size_t bytes) -> char* {
        char* p = ws + off;
        off = (off + bytes + 255) & ~(size_t)255;
        return p;
    };
    const size_t FB = (size_t)MPAD * 64 * 4;
    u32* F0 = (u32*)take(FB);
    u32* F1 = (u32*)take(FB);
    u32* F2 = (u32*)take(FB);
    u32* F4 = (u32*)take(FB);
    u32* F5 = (u32*)take(FB);
    u32* Wb = (u32*)take((size_t)KM5 * 64 * 32 * 4);
    int* cnt8_l = (int*)take((size_t)8 * M_SIMP * 4);
    int* cnt8_u = (int*)take((size_t)8 * M_SIMP * 4);
    int* rp_l  = (int*)take((size_t)(M_SIMP + 1) * 4);
    int* rp_u  = (int*)take((size_t)(M_SIMP + 1) * 4);
    u32* pe_l  = (u32*)take((size_t)NNZV * 4);
    u32* pe_u  = (u32*)take((size_t)NNZV * 4);
    uint2* cv_l = (uint2*)take((size_t)NNZV * 8);
    uint2* cv_u = (uint2*)take((size_t)NNZV * 8);
    int* bs_l = (int*)take(512);
    int* bs_u = (int*)take(512);

    hipMemsetAsync(cnt8_l, 0, (size_t)8 * M_SIMP * 4, stream);
    hipMemsetAsync(cnt8_u, 0, (size_t)8 * M_SIMP * 4, stream);

    // fused + striped: XCD-private hist | transpose | wb
    k_front<<<NBF, 256, 0, stream>>>(
        Ll_idx, Lu_idx, cnt8_l, cnt8_u, pe_l, pe_u, x, F0, theta, Wb);

    const int NBS = (M_SIMP + 1023) / 1024;   // 98
    dim3 gs(NBS, 2);
    k_scan1<<<gs, 256, 0, stream>>>(cnt8_l, rp_l, bs_l, cnt8_u, rp_u, bs_u, M_SIMP);
    k_scan3<<<gs, 256, 0, stream>>>(rp_l, bs_l, cnt8_l, rp_u, bs_u, cnt8_u, M_SIMP, NBS);

    dim3 gh(NBH, 2);
    k_scatcv<<<gh, 256, 0, stream>>>(Ll_idx, Ll_val, pe_l, cnt8_l, cv_l,
                                     Lu_idx, Lu_val, pe_u, cnt8_u, cv_u);

    const int NBM = (M_SIMP + 15) / 16;       // 6250
    dim3 gm(NBM, 2);
    k_spmm<<<gm, 256, 0, stream>>>(rp_l, cv_l, F0, F1,
                                   rp_u, cv_u, F0, F4);
    k_spmm<<<gm, 256, 0, stream>>>(rp_l, cv_l, F1, F2,
                                   rp_u, cv_u, F4, F5);

    k_gemm<<<NBT, 256, 0, stream>>>(F0, F1, F2, F4, F5, Wb, bias, out);
}